// Round 13
// baseline (334.882 us; speedup 1.0000x reference)
//
#include <hip/hip_runtime.h>
#include <hip/hip_bf16.h>
#include <stdint.h>

#define NN 100000
#define NE 1600000
#define IND 512
#define HID 128
#define OUTD 64
#define BN_EPS 1e-5f
#define NP 196       // ceil(NN/512) dst partitions
#define PSZ 512      // nodes per partition
#define PCAP 10240   // staging capacity per partition (mean 8192, +22 sigma)
#define BINCH 8192   // edges per bin block
#define NBIN 196     // ceil(NE/BINCH)
#define AGG1_GRID 2048

typedef __attribute__((ext_vector_type(8))) short short8v;
typedef __attribute__((ext_vector_type(4))) float f32x4;

// ---- fp32 -> bf16 (RNE) ----------------------------------------------------
__device__ __forceinline__ ushort f2bf(float f, float& back) {
  uint u = __float_as_uint(f);
  uint r = u + 0x7FFFu + ((u >> 16) & 1u);
  ushort h = (ushort)(r >> 16);
  back = __uint_as_float(((uint)h) << 16);
  return h;
}
__device__ __forceinline__ ushort f2bf_n(float f) {
  uint u = __float_as_uint(f);
  uint r = u + 0x7FFFu + ((u >> 16) & 1u);
  return (ushort)(r >> 16);
}
__device__ __forceinline__ float bf2f(ushort h) {
  return __uint_as_float(((uint)h) << 16);
}
__device__ __forceinline__ float bflo(uint v) { return __uint_as_float(v << 16); }
__device__ __forceinline__ float bfhi(uint v) { return __uint_as_float(v & 0xffff0000u); }
__device__ __forceinline__ uint packbf(float lo, float hi) {
  return (uint)f2bf_n(lo) | ((uint)f2bf_n(hi) << 16);
}

__device__ __forceinline__ int edge_at(const int* e32, int f, int i) {
  if (f) return (int)((const long long*)e32)[i];
  return e32[i];
}

// ---------------- K0: detect + prepW(W1^T hi/lo) + prepW2(W2^T hi/lo) -------
__global__ __launch_bounds__(256) void k_prep(const int* __restrict__ edges,
                                              const float* __restrict__ W1,
                                              const float* __restrict__ W2,
                                              int* __restrict__ flag,
                                              ushort* __restrict__ Wth,
                                              ushort* __restrict__ Wtl,
                                              ushort* __restrict__ W2th,
                                              ushort* __restrict__ W2tl) {
  const int bid = blockIdx.x, tid = threadIdx.x;
  if (bid == 0) {
    __shared__ int nz;
    if (tid == 0) nz = 0;
    __syncthreads();
    if (tid < 64) {
      int v = edges[2 * tid + 1];
      if (v != 0) atomicAdd(&nz, 1);
    }
    __syncthreads();
    if (tid == 0) *flag = (nz == 0) ? 1 : 0;  // 1 => int64
    return;
  }
  if (bid <= 256) {  // W1^T: [n][k], 128*512
    int i = (bid - 1) * 256 + tid;
    int n = i >> 9, k = i & 511;
    float w = W1[(size_t)k * HID + n];
    float back;
    Wth[i] = f2bf(w, back);
    Wtl[i] = f2bf_n(w - back);
    return;
  }
  {  // W2^T: [n][k], 64*128
    int j = (bid - 257) * 256 + tid;
    int n = j >> 7, k = j & 127;
    float w = W2[(size_t)k * OUTD + n];
    float back;
    W2th[j] = f2bf(w, back);
    W2tl[j] = f2bf_n(w - back);
  }
}

// ---------------- K1 body A: CSR bin pass (blocks 0..195) -------------------
__device__ void bin_body(int bid, ushort* smem16, const int* edges,
                         const int* flag, int* gCursor, int* staging) {
  int* cnt   = (int*)smem16;        // [NP]
  int* scn   = cnt + NP;            // [NP]
  int* base  = cnt + 2 * NP;        // [NP]
  int* cur   = cnt + 3 * NP;        // [NP]
  int* items = cnt + 4 * NP;        // [BINCH] -> (784+8192)*4 = 35,904 B
  const int tid = threadIdx.x;
  const int e0 = bid * BINCH;
  const int ecnt = min(BINCH, NE - e0);
  const int f = *flag;
  for (int i = tid; i < NP; i += 256) cnt[i] = 0;
  __syncthreads();
  for (int i = tid; i < ecnt; i += 256) {
    int d = edge_at(edges, f, NE + e0 + i);
    atomicAdd(&cnt[d >> 9], 1);
  }
  __syncthreads();
  if (tid == 0) {
    int s = 0;
    for (int p = 0; p < NP; ++p) { scn[p] = s; s += cnt[p]; }
  }
  __syncthreads();
  if (tid < NP) {
    base[tid] = (cnt[tid] > 0) ? atomicAdd(&gCursor[tid], cnt[tid]) : 0;
    cur[tid] = 0;
  }
  __syncthreads();
  for (int i = tid; i < ecnt; i += 256) {
    int d = edge_at(edges, f, NE + e0 + i);
    int s = edge_at(edges, f, e0 + i);
    int p = d >> 9;
    int lp = atomicAdd(&cur[p], 1);
    items[scn[p] + lp] = (s << 10) | (d & (PSZ - 1));
  }
  __syncthreads();
  for (int p = 0; p < NP; ++p) {
    int c = cnt[p];
    if (c == 0) continue;
    int gb = base[p];
    int* dst = staging + (size_t)p * PCAP;
    for (int i = tid; i < c; i += 256) {
      int gpos = gb + i;
      if (gpos < PCAP) dst[gpos] = items[scn[p] + i];
    }
  }
}

// ---------------- K1 body B: GEMM1 (r10 double-buffered, proven) ------------
__device__ void gemm1_body(int bid, ushort* smem, const float* x,
                           const ushort* Wth, const ushort* Wtl,
                           ushort* h1b) {
  ushort* sOut = smem;
  const int tid = threadIdx.x;
  const int lane = tid & 63, wid = tid >> 6;
  const int wr = wid >> 1, wc = wid & 1;
  const int lrow = lane & 15, lkg = lane >> 4;
  const int row0 = bid * 128;

  f32x4 acc[4][4];
#pragma unroll
  for (int m = 0; m < 4; ++m)
#pragma unroll
    for (int n = 0; n < 4; ++n) acc[m][n] = (f32x4){0.f, 0.f, 0.f, 0.f};

  float4 ra[4];
  uint4 rbh[2], rbl[2];

#pragma unroll
  for (int i = 0; i < 4; ++i) {
    int flat = i * 256 + tid, r = flat >> 3, kq = flat & 7;
    int grow = row0 + r; if (grow > NN - 1) grow = NN - 1;
    ra[i] = *(const float4*)(x + (size_t)grow * IND + kq * 4);
  }
#pragma unroll
  for (int i = 0; i < 2; ++i) {
    int flat = i * 256 + tid, col = flat >> 2, kc = flat & 3;
    rbh[i] = *(const uint4*)(Wth + (size_t)col * IND + kc * 8);
    rbl[i] = *(const uint4*)(Wtl + (size_t)col * IND + kc * 8);
  }
  {
    ushort* dAh = smem;
    ushort* dBh = smem + 5120;
    ushort* dBl = smem + 10240;
#pragma unroll
    for (int i = 0; i < 4; ++i) {
      int flat = i * 256 + tid, r = flat >> 3, kq = flat & 7;
      ushort4 hi;
      hi.x = f2bf_n(ra[i].x); hi.y = f2bf_n(ra[i].y);
      hi.z = f2bf_n(ra[i].z); hi.w = f2bf_n(ra[i].w);
      *(ushort4*)&dAh[r * 40 + kq * 4] = hi;
    }
#pragma unroll
    for (int i = 0; i < 2; ++i) {
      int flat = i * 256 + tid, col = flat >> 2, kc = flat & 3;
      *(uint4*)&dBh[col * 40 + kc * 8] = rbh[i];
      *(uint4*)&dBl[col * 40 + kc * 8] = rbl[i];
    }
  }

  int cur = 0;
  for (int s = 0; s < 16; ++s) {
    __syncthreads();
    if (s < 15) {
      int kt = (s + 1) * 32;
#pragma unroll
      for (int i = 0; i < 4; ++i) {
        int flat = i * 256 + tid, r = flat >> 3, kq = flat & 7;
        int grow = row0 + r; if (grow > NN - 1) grow = NN - 1;
        ra[i] = *(const float4*)(x + (size_t)grow * IND + kt + kq * 4);
      }
#pragma unroll
      for (int i = 0; i < 2; ++i) {
        int flat = i * 256 + tid, col = flat >> 2, kc = flat & 3;
        rbh[i] = *(const uint4*)(Wth + (size_t)col * IND + kt + kc * 8);
        rbl[i] = *(const uint4*)(Wtl + (size_t)col * IND + kt + kc * 8);
      }
    }
    {
      const ushort* bAh = smem + cur * 15360;
      const ushort* bBh = bAh + 5120;
      const ushort* bBl = bAh + 10240;
      short8v ah[4], bh[4], bl[4];
#pragma unroll
      for (int m = 0; m < 4; ++m) {
        int r = wr * 64 + m * 16 + lrow;
        ah[m] = *(const short8v*)&bAh[r * 40 + lkg * 8];
      }
#pragma unroll
      for (int n = 0; n < 4; ++n) {
        int c = wc * 64 + n * 16 + lrow;
        bh[n] = *(const short8v*)&bBh[c * 40 + lkg * 8];
        bl[n] = *(const short8v*)&bBl[c * 40 + lkg * 8];
      }
#pragma unroll
      for (int m = 0; m < 4; ++m)
#pragma unroll
        for (int n = 0; n < 4; ++n) {
          acc[m][n] = __builtin_amdgcn_mfma_f32_16x16x32_bf16(ah[m], bh[n], acc[m][n], 0, 0, 0);
          acc[m][n] = __builtin_amdgcn_mfma_f32_16x16x32_bf16(ah[m], bl[n], acc[m][n], 0, 0, 0);
        }
    }
    if (s < 15) {
      ushort* dAh = smem + (cur ^ 1) * 15360;
      ushort* dBh = dAh + 5120;
      ushort* dBl = dAh + 10240;
#pragma unroll
      for (int i = 0; i < 4; ++i) {
        int flat = i * 256 + tid, r = flat >> 3, kq = flat & 7;
        ushort4 hi;
        hi.x = f2bf_n(ra[i].x); hi.y = f2bf_n(ra[i].y);
        hi.z = f2bf_n(ra[i].z); hi.w = f2bf_n(ra[i].w);
        *(ushort4*)&dAh[r * 40 + kq * 4] = hi;
      }
#pragma unroll
      for (int i = 0; i < 2; ++i) {
        int flat = i * 256 + tid, col = flat >> 2, kc = flat & 3;
        *(uint4*)&dBh[col * 40 + kc * 8] = rbh[i];
        *(uint4*)&dBl[col * 40 + kc * 8] = rbl[i];
      }
    }
    cur ^= 1;
  }

  __syncthreads();
#pragma unroll
  for (int m = 0; m < 4; ++m)
#pragma unroll
    for (int i = 0; i < 4; ++i) {
      int lr = wr * 64 + m * 16 + lkg * 4 + i;
#pragma unroll
      for (int n = 0; n < 4; ++n)
        sOut[lr * 136 + wc * 64 + n * 16 + lrow] = f2bf_n(acc[m][n][i]);
    }
  __syncthreads();
#pragma unroll
  for (int j = 0; j < 8; ++j) {
    int flat = j * 256 + tid;
    int r = flat >> 4, c = flat & 15;
    int grow = row0 + r;
    if (grow < NN)
      *(uint4*)(h1b + (size_t)grow * HID + c * 8) =
          *(const uint4*)&sOut[r * 136 + c * 8];
  }
}

// ---------------- K1: fused bin (first) + gemm1 -----------------------------
__global__ __launch_bounds__(256) void k_fused1(const float* __restrict__ x,
                                                const ushort* __restrict__ Wth,
                                                const ushort* __restrict__ Wtl,
                                                const int* __restrict__ edges,
                                                const int* __restrict__ flag,
                                                int* __restrict__ gCursor,
                                                int* __restrict__ staging,
                                                ushort* __restrict__ h1b) {
  __shared__ __align__(16) ushort smem[30720];
  if (blockIdx.x < NBIN)
    bin_body(blockIdx.x, smem, edges, flag, gCursor, staging);
  else
    gemm1_body(blockIdx.x - NBIN, smem, x, Wth, Wtl, h1b);
}

// ---------------- CSR pass 2: per-partition counting sort (self-scanned) ----
__global__ __launch_bounds__(256) void k_csrpart(const int* __restrict__ staging,
                                                 const int* __restrict__ gCursor,
                                                 int* __restrict__ offsets,
                                                 int* __restrict__ csr_src) {
  __shared__ int cnt[PSZ];
  __shared__ int cur[PSZ];
  __shared__ int tsum[256];
  __shared__ int gc[256];
  __shared__ int srcbuf[PCAP];   // 40 KB
  const int tid = threadIdx.x;
  const int p = blockIdx.x;
  gc[tid] = (tid < NP) ? min(gCursor[tid], PCAP) : 0;
  for (int i = tid; i < PSZ; i += 256) { cnt[i] = 0; cur[i] = 0; }
  if (p == NP - 1 && tid == 0) offsets[NN] = NE;
  __syncthreads();
  // inclusive scan of gc (parallel; replaces serial partBase pass)
  for (int off = 1; off < 256; off <<= 1) {
    int t = (tid >= off) ? gc[tid - off] : 0;
    __syncthreads();
    gc[tid] += t;
    __syncthreads();
  }
  const int tot = min(gCursor[p], PCAP);
  const int gbase = gc[p] - tot;
  const int* st = staging + (size_t)p * PCAP;
  for (int i = tid; i < tot; i += 256) atomicAdd(&cnt[st[i] & (PSZ - 1)], 1);
  __syncthreads();
  int b0 = tid * 2;
  int c0 = cnt[b0], c1 = cnt[b0 + 1];
  int ls = c0 + c1;
  tsum[tid] = ls;
  __syncthreads();
  for (int off = 1; off < 256; off <<= 1) {
    int t = (tid >= off) ? tsum[tid - off] : 0;
    __syncthreads();
    tsum[tid] += t;
    __syncthreads();
  }
  int ebase = tsum[tid] - ls;
  cnt[b0] = ebase;
  cnt[b0 + 1] = ebase + c0;
  __syncthreads();
  for (int i = tid; i < PSZ; i += 256) {
    int node = p * PSZ + i;
    if (node < NN) offsets[node] = gbase + cnt[i];
  }
  for (int i = tid; i < tot; i += 256) {
    int item = st[i];
    int dl = item & (PSZ - 1);
    int lp = atomicAdd(&cur[dl], 1);
    srcbuf[cnt[dl] + lp] = item >> 10;
  }
  __syncthreads();
  for (int i = tid; i < tot; i += 256) csr_src[gbase + i] = srcbuf[i];
}

// ---------------- Agg1 (+b1) + fused BN stats -------------------------------
// Grid-stride (2048 blocks). Per node: one coalesced 64-lane index load into
// wave-private LDS breaks the index->gather dependency chain; gathers for the
// whole node then pipeline back-to-back. BN partials accumulate in LDS, one
// set of 256 global atomics per block (replaces the k_bnstats pass).
__global__ __launch_bounds__(256) void k_agg1(const ushort* __restrict__ h1b,
                                              const int* __restrict__ offsets,
                                              const int* __restrict__ csr_src,
                                              const float* __restrict__ b1,
                                              ushort* __restrict__ aggb,
                                              float* __restrict__ gsum,
                                              float* __restrict__ gsq) {
  __shared__ float sSum[128], sSq[128];
  __shared__ int sidx[4][64];
  const int tid = threadIdx.x, w = tid >> 6, lane = tid & 63;
  const int half = lane >> 5, ch = lane & 31;
  for (int i = tid; i < 128; i += 256) { sSum[i] = 0.f; sSq[i] = 0.f; }
  __syncthreads();
  const uint2* h = (const uint2*)h1b;  // 32 uint2 per row (128 bf16)
  float4 b = *(const float4*)(b1 + 4 * ch);
  for (int n = blockIdx.x * 4 + w; n < NN; n += AGG1_GRID * 4) {
    int beg = offsets[n], end = offsets[n + 1], deg = end - beg;
    int dcap = min(deg, 64);
    if (lane < dcap) sidx[w][lane] = csr_src[beg + lane];
    float4 a = {0.f, 0.f, 0.f, 0.f}, a2 = {0.f, 0.f, 0.f, 0.f};
    int i = half;
    for (; i + 2 < dcap; i += 4) {
      int s0 = sidx[w][i], s1 = sidx[w][i + 2];
      uint2 v0 = h[(size_t)s0 * 32 + ch];
      uint2 v1 = h[(size_t)s1 * 32 + ch];
      a.x += bflo(v0.x); a.y += bfhi(v0.x); a.z += bflo(v0.y); a.w += bfhi(v0.y);
      a2.x += bflo(v1.x); a2.y += bfhi(v1.x); a2.z += bflo(v1.y); a2.w += bfhi(v1.y);
    }
    if (i < dcap) {
      uint2 v = h[(size_t)sidx[w][i] * 32 + ch];
      a.x += bflo(v.x); a.y += bfhi(v.x); a.z += bflo(v.y); a.w += bfhi(v.y);
    }
    for (int j = 64 + half; j < deg; j += 2) {  // deg>64 tail (essentially never)
      uint2 v = h[(size_t)csr_src[beg + j] * 32 + ch];
      a.x += bflo(v.x); a.y += bfhi(v.x); a.z += bflo(v.y); a.w += bfhi(v.y);
    }
    a.x += a2.x; a.y += a2.y; a.z += a2.z; a.w += a2.w;
    a.x += __shfl_xor(a.x, 32);
    a.y += __shfl_xor(a.y, 32);
    a.z += __shfl_xor(a.z, 32);
    a.w += __shfl_xor(a.w, 32);
    if (half == 0) {
      float c0 = a.x + b.x, c1 = a.y + b.y, c2 = a.z + b.z, c3 = a.w + b.w;
      uint2 o;
      o.x = packbf(c0, c1);
      o.y = packbf(c2, c3);
      ((uint2*)aggb)[(size_t)n * 32 + ch] = o;
      atomicAdd(&sSum[4 * ch + 0], c0); atomicAdd(&sSq[4 * ch + 0], c0 * c0);
      atomicAdd(&sSum[4 * ch + 1], c1); atomicAdd(&sSq[4 * ch + 1], c1 * c1);
      atomicAdd(&sSum[4 * ch + 2], c2); atomicAdd(&sSq[4 * ch + 2], c2 * c2);
      atomicAdd(&sSum[4 * ch + 3], c3); atomicAdd(&sSq[4 * ch + 3], c3 * c3);
    }
  }
  __syncthreads();
  if (tid < 128) {
    atomicAdd(&gsum[tid], sSum[tid]);
    atomicAdd(&gsq[tid], sSq[tid]);
  }
}

// ---------------- GEMM2 via MFMA (BN-finalize fused in-block) ---------------
__global__ __launch_bounds__(256) void k_gemm2m(const ushort* __restrict__ aggb,
                                                const ushort* __restrict__ W2th,
                                                const ushort* __restrict__ W2tl,
                                                const float* __restrict__ gsum,
                                                const float* __restrict__ gsq,
                                                const float* __restrict__ gamma,
                                                const float* __restrict__ beta,
                                                ushort* __restrict__ h2b) {
  __shared__ __align__(16) ushort smem[27648]; // Bh 8704 | Bl 8704 | Adbuf 10240
  __shared__ float isgS[128], bbS[128];
  ushort* sBh = smem;            // [64][136]
  ushort* sBl = smem + 8704;     // [64][136]
  ushort* sA  = smem + 17408;    // 2 x [128][40]
  ushort* sOut = sA;             // epilogue alias: [128][72]
  const int tid = threadIdx.x;
  const int lane = tid & 63, wid = tid >> 6;
  const int wr = wid >> 1, wc = wid & 1;
  const int lrow = lane & 15, lkg = lane >> 4;
  const int row0 = blockIdx.x * 128;

  if (tid < 128) {  // fused bnfin (redundant per block, trivial)
    float mean = gsum[tid] * (1.f / NN);
    float var = fmaxf(gsq[tid] * (1.f / NN) - mean * mean, 0.f);
    float inv = 1.f / sqrtf(var + BN_EPS);
    float g = gamma[tid] * inv;
    isgS[tid] = g;
    bbS[tid] = beta[tid] - mean * g;
  }
#pragma unroll
  for (int i = 0; i < 4; ++i) {
    int c = i * 256 + tid;
    int n = c >> 4, kq = c & 15;
    *(uint4*)&sBh[n * 136 + kq * 8] = *(const uint4*)(W2th + (size_t)n * HID + kq * 8);
    *(uint4*)&sBl[n * 136 + kq * 8] = *(const uint4*)(W2tl + (size_t)n * HID + kq * 8);
  }

  f32x4 acc[4][2];
#pragma unroll
  for (int m = 0; m < 4; ++m)
#pragma unroll
    for (int n = 0; n < 2; ++n) acc[m][n] = (f32x4){0.f, 0.f, 0.f, 0.f};

  uint4 rA[2];
#pragma unroll
  for (int i = 0; i < 2; ++i) {
    int c = i * 256 + tid;
    int r = c >> 2, cq = c & 3;
    int grow = row0 + r; if (grow > NN - 1) grow = NN - 1;
    rA[i] = *(const uint4*)(aggb + (size_t)grow * HID + cq * 8);
  }
  __syncthreads();  // isgS/bbS + B visible

  {
    ushort* dA = sA;
#pragma unroll
    for (int i = 0; i < 2; ++i) {
      int c = i * 256 + tid;
      int r = c >> 2, cq = c & 3;
      int k0 = cq * 8;
      uint4 v = rA[i];
      uint o[4];
      const uint* vv = (const uint*)&v;
#pragma unroll
      for (int j = 0; j < 4; ++j) {
        float lo = bflo(vv[j]), hi = bfhi(vv[j]);
        lo = fmaxf(fmaf(lo, isgS[k0 + 2 * j], bbS[k0 + 2 * j]), 0.f);
        hi = fmaxf(fmaf(hi, isgS[k0 + 2 * j + 1], bbS[k0 + 2 * j + 1]), 0.f);
        o[j] = packbf(lo, hi);
      }
      *(uint4*)&dA[r * 40 + cq * 8] = *(const uint4*)o;
    }
  }

  int cur = 0;
  for (int s = 0; s < 4; ++s) {
    __syncthreads();
    const int kt = s * 32;
    if (s < 3) {
      int ktn = kt + 32;
#pragma unroll
      for (int i = 0; i < 2; ++i) {
        int c = i * 256 + tid;
        int r = c >> 2, cq = c & 3;
        int grow = row0 + r; if (grow > NN - 1) grow = NN - 1;
        rA[i] = *(const uint4*)(aggb + (size_t)grow * HID + ktn + cq * 8);
      }
    }
    {
      const ushort* bA = sA + cur * 5120;
      short8v ah[4], bh[2], bl[2];
#pragma unroll
      for (int m = 0; m < 4; ++m) {
        int r = wr * 64 + m * 16 + lrow;
        ah[m] = *(const short8v*)&bA[r * 40 + lkg * 8];
      }
#pragma unroll
      for (int n = 0; n < 2; ++n) {
        int c = wc * 32 + n * 16 + lrow;
        bh[n] = *(const short8v*)&sBh[c * 136 + kt + lkg * 8];
        bl[n] = *(const short8v*)&sBl[c * 136 + kt + lkg * 8];
      }
#pragma unroll
      for (int m = 0; m < 4; ++m)
#pragma unroll
        for (int n = 0; n < 2; ++n) {
          acc[m][n] = __builtin_amdgcn_mfma_f32_16x16x32_bf16(ah[m], bh[n], acc[m][n], 0, 0, 0);
          acc[m][n] = __builtin_amdgcn_mfma_f32_16x16x32_bf16(ah[m], bl[n], acc[m][n], 0, 0, 0);
        }
    }
    if (s < 3) {
      ushort* dA = sA + (cur ^ 1) * 5120;
      int k0b = (s + 1) * 32;
#pragma unroll
      for (int i = 0; i < 2; ++i) {
        int c = i * 256 + tid;
        int r = c >> 2, cq = c & 3;
        int k0 = k0b + cq * 8;
        uint4 v = rA[i];
        uint o[4];
        const uint* vv = (const uint*)&v;
#pragma unroll
        for (int j = 0; j < 4; ++j) {
          float lo = bflo(vv[j]), hi = bfhi(vv[j]);
          lo = fmaxf(fmaf(lo, isgS[k0 + 2 * j], bbS[k0 + 2 * j]), 0.f);
          hi = fmaxf(fmaf(hi, isgS[k0 + 2 * j + 1], bbS[k0 + 2 * j + 1]), 0.f);
          o[j] = packbf(lo, hi);
        }
        *(uint4*)&dA[r * 40 + cq * 8] = *(const uint4*)o;
      }
    }
    cur ^= 1;
  }

  __syncthreads();
#pragma unroll
  for (int m = 0; m < 4; ++m)
#pragma unroll
    for (int i = 0; i < 4; ++i) {
      int lr = wr * 64 + m * 16 + lkg * 4 + i;
#pragma unroll
      for (int n = 0; n < 2; ++n)
        sOut[lr * 72 + wc * 32 + n * 16 + lrow] = f2bf_n(acc[m][n][i]);
    }
  __syncthreads();
#pragma unroll
  for (int i = 0; i < 4; ++i) {
    int c = i * 256 + tid;
    int r = c >> 3, cq = c & 7;
    int grow = row0 + r;
    if (grow < NN)
      *(uint4*)(h2b + (size_t)grow * OUTD + cq * 8) =
          *(const uint4*)&sOut[r * 72 + cq * 8];
  }
}

// ---------------- Agg2 + b2 + L2 normalize + fp32 store ---------------------
__global__ __launch_bounds__(256) void k_agg2norm(const ushort* __restrict__ h2b,
                                                  const int* __restrict__ offsets,
                                                  const int* __restrict__ csr_src,
                                                  const float* __restrict__ b2,
                                                  float* __restrict__ out) {
  __shared__ int sidx[4][64];
  int tid = threadIdx.x, w = tid >> 6, lane = tid & 63;
  int n = blockIdx.x * 4 + w;
  if (n >= NN) return;
  int beg = offsets[n], end = offsets[n + 1], deg = end - beg;
  int dcap = min(deg, 64);
  if (lane < dcap) sidx[w][lane] = csr_src[beg + lane];
  int half = lane >> 5, ch = lane & 31;
  const uint* h = (const uint*)h2b;  // 32 uints per row (64 bf16)
  float2 a = {0.f, 0.f}, a2 = {0.f, 0.f};
  int i = half;
  for (; i + 2 < dcap; i += 4) {
    uint v0 = h[(size_t)sidx[w][i] * 32 + ch];
    uint v1 = h[(size_t)sidx[w][i + 2] * 32 + ch];
    a.x += bflo(v0); a.y += bfhi(v0);
    a2.x += bflo(v1); a2.y += bfhi(v1);
  }
  if (i < dcap) {
    uint v = h[(size_t)sidx[w][i] * 32 + ch];
    a.x += bflo(v); a.y += bfhi(v);
  }
  for (int j = 64 + half; j < deg; j += 2) {
    uint v = h[(size_t)csr_src[beg + j] * 32 + ch];
    a.x += bflo(v); a.y += bfhi(v);
  }
  a.x += a2.x; a.y += a2.y;
  a.x += __shfl_xor(a.x, 32);
  a.y += __shfl_xor(a.y, 32);
  float2 b = *(const float2*)(b2 + 2 * ch);
  a.x += b.x; a.y += b.y;
  float q = a.x * a.x + a.y * a.y;
#pragma unroll
  for (int off = 16; off > 0; off >>= 1) q += __shfl_xor(q, off);
  float norm = sqrtf(q);
  float scale = 1.f / fmaxf(norm, 1e-12f);
  if (half == 0) {
    float2 o = {a.x * scale, a.y * scale};
    *(float2*)(out + (size_t)n * OUTD + 2 * ch) = o;
  }
}

// ---------------- launch ----------------------------------------------------
extern "C" void kernel_launch(void* const* d_in, const int* in_sizes, int n_in,
                              void* d_out, int out_size, void* d_ws, size_t ws_size,
                              hipStream_t stream) {
  const float* x     = (const float*)d_in[0];
  const int*   edges = (const int*)d_in[1];
  const float* W1    = (const float*)d_in[2];
  const float* b1    = (const float*)d_in[3];
  const float* W2    = (const float*)d_in[4];
  const float* b2    = (const float*)d_in[5];
  const float* gamma = (const float*)d_in[6];
  const float* beta  = (const float*)d_in[7];

  char* ws = (char*)d_ws;
  ushort* h1b     = (ushort*)(ws);                // 25.6 MB
  ushort* aggb    = (ushort*)(ws + 26000000);     // 25.6 MB (bf16)
  int*    csr_src = (int*)(ws + 77500000);        // 6.4 MB
  int*    offsets = (int*)(ws + 84000000);        // 100001 ints
  int*    staging = (int*)(ws + 84400128);        // 196*10240*4 = 8,028,160 B
  int*    gCursor = (int*)(ws + 92428544);        // 196 ints (1 KB region)
  float*  gsum    = (float*)(ws + 92429568);      // 128 f
  float*  gsq     = (float*)(ws + 92430080);      // 128 f
  int*    eflag   = (int*)(ws + 92431616);        // 1 int
  ushort* Wth     = (ushort*)(ws + 92432128);     // 128 KB
  ushort* Wtl     = (ushort*)(ws + 92563200);     // 128 KB
  ushort* W2th    = (ushort*)(ws + 92694272);     // 16 KB
  ushort* W2tl    = (ushort*)(ws + 92710656);     // 16 KB
  ushort* h2b     = h1b;                          // reuse (h1b dead after agg1)

  if (ws_size < 92727040) return;  // scratch layout requirement

  // zero gCursor (784 B) + gsum + gsq (covered by 2 KB from gCursor base)
  hipMemsetAsync(gCursor, 0, 2048, stream);

  k_prep<<<289, 256, 0, stream>>>(edges, W1, W2, eflag, Wth, Wtl, W2th, W2tl);
  k_fused1<<<NBIN + 782, 256, 0, stream>>>(x, Wth, Wtl, edges, eflag,
                                           gCursor, staging, h1b);
  k_csrpart<<<NP, 256, 0, stream>>>(staging, gCursor, offsets, csr_src);
  k_agg1<<<AGG1_GRID, 256, 0, stream>>>(h1b, offsets, csr_src, b1, aggb, gsum, gsq);
  k_gemm2m<<<782, 256, 0, stream>>>(aggb, W2th, W2tl, gsum, gsq, gamma, beta, h2b);
  k_agg2norm<<<25000, 256, 0, stream>>>(h2b, offsets, csr_src, b2,
                                        (float*)d_out);
}

// Round 14
// 306.988 us; speedup vs baseline: 1.0909x; 1.0909x over previous
//
#include <hip/hip_runtime.h>
#include <hip/hip_bf16.h>
#include <stdint.h>

#define NN 100000
#define NE 1600000
#define IND 512
#define HID 128
#define OUTD 64
#define BN_EPS 1e-5f
#define NP 98        // ceil(NN/1024) dst partitions
#define PSZ 1024     // nodes per partition
#define PCAP 20480   // staging capacity per partition
#define BINCH 8192   // edges per bin block
#define NBIN 196     // ceil(NE/BINCH)

typedef __attribute__((ext_vector_type(8))) short short8v;
typedef __attribute__((ext_vector_type(4))) float f32x4;

// ---- fp32 -> bf16 (RNE) ----------------------------------------------------
__device__ __forceinline__ ushort f2bf(float f, float& back) {
  uint u = __float_as_uint(f);
  uint r = u + 0x7FFFu + ((u >> 16) & 1u);
  ushort h = (ushort)(r >> 16);
  back = __uint_as_float(((uint)h) << 16);
  return h;
}
__device__ __forceinline__ ushort f2bf_n(float f) {
  uint u = __float_as_uint(f);
  uint r = u + 0x7FFFu + ((u >> 16) & 1u);
  return (ushort)(r >> 16);
}
__device__ __forceinline__ float bf2f(ushort h) {
  return __uint_as_float(((uint)h) << 16);
}
__device__ __forceinline__ float bflo(uint v) { return __uint_as_float(v << 16); }
__device__ __forceinline__ float bfhi(uint v) { return __uint_as_float(v & 0xffff0000u); }
__device__ __forceinline__ uint packbf(float lo, float hi) {
  return (uint)f2bf_n(lo) | ((uint)f2bf_n(hi) << 16);
}

__device__ __forceinline__ int edge_at(const int* e32, int f, int i) {
  if (f) return (int)((const long long*)e32)[i];
  return e32[i];
}

// ---------------- K0: detect + prepW(W1^T hi/lo) + prepW2(W2^T hi/lo) -------
__global__ __launch_bounds__(256) void k_prep(const int* __restrict__ edges,
                                              const float* __restrict__ W1,
                                              const float* __restrict__ W2,
                                              int* __restrict__ flag,
                                              ushort* __restrict__ Wth,
                                              ushort* __restrict__ Wtl,
                                              ushort* __restrict__ W2th,
                                              ushort* __restrict__ W2tl) {
  const int bid = blockIdx.x, tid = threadIdx.x;
  if (bid == 0) {
    __shared__ int nz;
    if (tid == 0) nz = 0;
    __syncthreads();
    if (tid < 64) {
      int v = edges[2 * tid + 1];
      if (v != 0) atomicAdd(&nz, 1);
    }
    __syncthreads();
    if (tid == 0) *flag = (nz == 0) ? 1 : 0;  // 1 => int64
    return;
  }
  if (bid <= 256) {  // W1^T: [n][k], 128*512
    int i = (bid - 1) * 256 + tid;
    int n = i >> 9, k = i & 511;
    float w = W1[(size_t)k * HID + n];
    float back;
    Wth[i] = f2bf(w, back);
    Wtl[i] = f2bf_n(w - back);
    return;
  }
  {  // W2^T: [n][k], 64*128
    int j = (bid - 257) * 256 + tid;
    int n = j >> 7, k = j & 127;
    float w = W2[(size_t)k * OUTD + n];
    float back;
    W2th[j] = f2bf(w, back);
    W2tl[j] = f2bf_n(w - back);
  }
}

// ---------------- K1 body A: CSR bin pass (blocks 0..195) -------------------
__device__ void bin_body(int bid, ushort* smem16, const int* edges,
                         const int* flag, int* gCursor, int* staging) {
  int* cnt   = (int*)smem16;        // [NP]
  int* scn   = cnt + 128;           // [NP]
  int* base  = cnt + 256;           // [NP]
  int* cur   = cnt + 384;           // [NP]
  int* items = cnt + 512;           // [BINCH]
  const int tid = threadIdx.x;
  const int e0 = bid * BINCH;
  const int ecnt = min(BINCH, NE - e0);
  const int f = *flag;
  for (int i = tid; i < NP; i += 256) cnt[i] = 0;
  __syncthreads();
  for (int i = tid; i < ecnt; i += 256) {
    int d = edge_at(edges, f, NE + e0 + i);
    atomicAdd(&cnt[d >> 10], 1);
  }
  __syncthreads();
  if (tid == 0) {
    int s = 0;
    for (int p = 0; p < NP; ++p) { scn[p] = s; s += cnt[p]; }
  }
  __syncthreads();
  if (tid < NP) {
    base[tid] = (cnt[tid] > 0) ? atomicAdd(&gCursor[tid], cnt[tid]) : 0;
    cur[tid] = 0;
  }
  __syncthreads();
  for (int i = tid; i < ecnt; i += 256) {
    int d = edge_at(edges, f, NE + e0 + i);
    int s = edge_at(edges, f, e0 + i);
    int p = d >> 10;
    int lp = atomicAdd(&cur[p], 1);
    items[scn[p] + lp] = (s << 10) | (d & (PSZ - 1));
  }
  __syncthreads();
  for (int p = 0; p < NP; ++p) {
    int c = cnt[p];
    if (c == 0) continue;
    int gb = base[p];
    int* dst = staging + (size_t)p * PCAP;
    for (int i = tid; i < c; i += 256) {
      int gpos = gb + i;
      if (gpos < PCAP) dst[gpos] = items[scn[p] + i];
    }
  }
}

// ---------------- K1 body B: GEMM1, depth-2 A pipeline ----------------------
// BM=128, BN=128, BK=32, 16 K-steps. A loads issued 2 tiles ahead (regsets
// raA0/raA1), held in-flight across RAW s_barrier (no vmcnt drain — the
// __syncthreads drain was the ~600cyc/step stall). B (L2-resident) depth-1.
// ds_write -> lgkmcnt(0) -> sched_barrier -> s_barrier -> sched_barrier per
// the m201 recipe; MFMA ds_reads remain compiler-managed.
__device__ __forceinline__ void g1_loadA(const float* x, int row0, int tid,
                                         int kt, float4 ra[4]) {
#pragma unroll
  for (int i = 0; i < 4; ++i) {
    int flat = i * 256 + tid, r = flat >> 3, kq = flat & 7;
    int grow = row0 + r; if (grow > NN - 1) grow = NN - 1;
    ra[i] = *(const float4*)(x + (size_t)grow * IND + kt + kq * 4);
  }
}
__device__ __forceinline__ void g1_loadB(const ushort* Wth, const ushort* Wtl,
                                         int tid, int kt, uint4 rbh[2], uint4 rbl[2]) {
#pragma unroll
  for (int i = 0; i < 2; ++i) {
    int flat = i * 256 + tid, col = flat >> 2, kc = flat & 3;
    rbh[i] = *(const uint4*)(Wth + (size_t)col * IND + kt + kc * 8);
    rbl[i] = *(const uint4*)(Wtl + (size_t)col * IND + kt + kc * 8);
  }
}
__device__ __forceinline__ void g1_storeA(ushort* dAh, int tid, const float4 ra[4]) {
#pragma unroll
  for (int i = 0; i < 4; ++i) {
    int flat = i * 256 + tid, r = flat >> 3, kq = flat & 7;
    ushort4 hi;
    hi.x = f2bf_n(ra[i].x); hi.y = f2bf_n(ra[i].y);
    hi.z = f2bf_n(ra[i].z); hi.w = f2bf_n(ra[i].w);
    *(ushort4*)&dAh[r * 40 + kq * 4] = hi;
  }
}
__device__ __forceinline__ void g1_storeB(ushort* dBh, ushort* dBl, int tid,
                                          const uint4 rbh[2], const uint4 rbl[2]) {
#pragma unroll
  for (int i = 0; i < 2; ++i) {
    int flat = i * 256 + tid, col = flat >> 2, kc = flat & 3;
    *(uint4*)&dBh[col * 40 + kc * 8] = rbh[i];
    *(uint4*)&dBl[col * 40 + kc * 8] = rbl[i];
  }
}
__device__ __forceinline__ void g1_mfma(const ushort* buf, int wr, int wc,
                                        int lrow, int lkg, f32x4 acc[4][4]) {
  const ushort* bAh = buf;
  const ushort* bBh = buf + 5120;
  const ushort* bBl = buf + 10240;
  short8v ah[4], bh[4], bl[4];
#pragma unroll
  for (int m = 0; m < 4; ++m) {
    int r = wr * 64 + m * 16 + lrow;
    ah[m] = *(const short8v*)&bAh[r * 40 + lkg * 8];
  }
#pragma unroll
  for (int n = 0; n < 4; ++n) {
    int c = wc * 64 + n * 16 + lrow;
    bh[n] = *(const short8v*)&bBh[c * 40 + lkg * 8];
    bl[n] = *(const short8v*)&bBl[c * 40 + lkg * 8];
  }
#pragma unroll
  for (int m = 0; m < 4; ++m)
#pragma unroll
    for (int n = 0; n < 4; ++n) {
      acc[m][n] = __builtin_amdgcn_mfma_f32_16x16x32_bf16(ah[m], bh[n], acc[m][n], 0, 0, 0);
      acc[m][n] = __builtin_amdgcn_mfma_f32_16x16x32_bf16(ah[m], bl[n], acc[m][n], 0, 0, 0);
    }
}
__device__ __forceinline__ void g1_barrier() {
  asm volatile("s_waitcnt lgkmcnt(0)");
  __builtin_amdgcn_sched_barrier(0);
  __builtin_amdgcn_s_barrier();
  __builtin_amdgcn_sched_barrier(0);
}

__device__ void gemm1_body(int bid, ushort* smem, const float* x,
                           const ushort* Wth, const ushort* Wtl,
                           ushort* h1b) {
  ushort* sOut = smem;
  const int tid = threadIdx.x;
  const int lane = tid & 63, wid = tid >> 6;
  const int wr = wid >> 1, wc = wid & 1;
  const int lrow = lane & 15, lkg = lane >> 4;
  const int row0 = bid * 128;
  ushort* B0 = smem;            // buffer 0: Ah | Bh | Bl (15360 u16)
  ushort* B1 = smem + 15360;    // buffer 1

  f32x4 acc[4][4];
#pragma unroll
  for (int m = 0; m < 4; ++m)
#pragma unroll
    for (int n = 0; n < 4; ++n) acc[m][n] = (f32x4){0.f, 0.f, 0.f, 0.f};

  float4 raA0[4], raA1[4];      // depth-2 A staging (named: static indexing)
  uint4 rbh[2], rbl[2];         // depth-1 B staging

  // ---- prologue: T0 -> raA0, T1 -> raA1 (stays in flight), B T0
  g1_loadA(x, row0, tid, 0, raA0);
  g1_loadA(x, row0, tid, 32, raA1);
  g1_loadB(Wth, Wtl, tid, 0, rbh, rbl);
  g1_storeA(B0, tid, raA0);                 // waits raA0 loads only
  g1_storeB(B0 + 5120, B0 + 10240, tid, rbh, rbl);
  g1_barrier();

  // ---- main loop: 8 x 2 steps, fully static buffer/set selection
  for (int ss = 0; ss < 8; ++ss) {
    int s0 = 2 * ss;       // even step: MFMA B0, convert raA1 -> B1, load->raA0
    if (s0 + 2 < 16) g1_loadA(x, row0, tid, (s0 + 2) * 32, raA0);
    g1_loadB(Wth, Wtl, tid, (s0 + 1) * 32, rbh, rbl);
    g1_mfma(B0, wr, wc, lrow, lkg, acc);
    g1_storeA(B1, tid, raA1);               // waits raA1 (issued 2 steps ago)
    g1_storeB(B1 + 5120, B1 + 10240, tid, rbh, rbl);
    g1_barrier();

    int s1 = s0 + 1;       // odd step: MFMA B1, convert raA0 -> B0, load->raA1
    if (s1 + 2 < 16) {
      g1_loadA(x, row0, tid, (s1 + 2) * 32, raA1);
    }
    if (s1 + 1 < 16) {
      g1_loadB(Wth, Wtl, tid, (s1 + 1) * 32, rbh, rbl);
    }
    g1_mfma(B1, wr, wc, lrow, lkg, acc);
    if (s1 + 1 < 16) {
      g1_storeA(B0, tid, raA0);
      g1_storeB(B0 + 5120, B0 + 10240, tid, rbh, rbl);
      g1_barrier();
    }
  }

  // ---- epilogue: stage in LDS, flush coalesced
  __syncthreads();
#pragma unroll
  for (int m = 0; m < 4; ++m)
#pragma unroll
    for (int i = 0; i < 4; ++i) {
      int lr = wr * 64 + m * 16 + lkg * 4 + i;
#pragma unroll
      for (int n = 0; n < 4; ++n)
        sOut[lr * 136 + wc * 64 + n * 16 + lrow] = f2bf_n(acc[m][n][i]);
    }
  __syncthreads();
#pragma unroll
  for (int j = 0; j < 8; ++j) {
    int flat = j * 256 + tid;
    int r = flat >> 4, c = flat & 15;
    int grow = row0 + r;
    if (grow < NN)
      *(uint4*)(h1b + (size_t)grow * HID + c * 8) =
          *(const uint4*)&sOut[r * 136 + c * 8];
  }
}

// ---------------- K1: fused bin (first) + gemm1 -----------------------------
__global__ __launch_bounds__(256) void k_fused1(const float* __restrict__ x,
                                                const ushort* __restrict__ Wth,
                                                const ushort* __restrict__ Wtl,
                                                const int* __restrict__ edges,
                                                const int* __restrict__ flag,
                                                int* __restrict__ gCursor,
                                                int* __restrict__ staging,
                                                ushort* __restrict__ h1b) {
  __shared__ __align__(16) ushort smem[30720];
  if (blockIdx.x < NBIN)
    bin_body(blockIdx.x, smem, edges, flag, gCursor, staging);
  else
    gemm1_body(blockIdx.x - NBIN, smem, x, Wth, Wtl, h1b);
}

// ---------------- CSR pass 2: per-partition counting sort (self-scanned) ----
__global__ __launch_bounds__(256) void k_csrpart(const int* __restrict__ staging,
                                                 const int* __restrict__ gCursor,
                                                 int* __restrict__ offsets,
                                                 int* __restrict__ csr_src) {
  __shared__ int cnt[PSZ];
  __shared__ int cur[PSZ];
  __shared__ int tsum[256];
  __shared__ int srcbuf[PCAP];   // 80 KB
  __shared__ int gbase_s;
  const int tid = threadIdx.x;
  const int p = blockIdx.x;
  if (tid == 0) {
    int s = 0;
    for (int q = 0; q < p; ++q) s += min(gCursor[q], PCAP);
    gbase_s = s;
    if (p == NP - 1) offsets[NN] = NE;
  }
  const int tot = min(gCursor[p], PCAP);
  const int* st = staging + (size_t)p * PCAP;
  for (int i = tid; i < PSZ; i += 256) { cnt[i] = 0; cur[i] = 0; }
  __syncthreads();
  const int gbase = gbase_s;
  for (int i = tid; i < tot; i += 256) atomicAdd(&cnt[st[i] & (PSZ - 1)], 1);
  __syncthreads();
  int b0 = tid * 4;
  int c0 = cnt[b0], c1 = cnt[b0 + 1], c2 = cnt[b0 + 2], c3 = cnt[b0 + 3];
  int ls = c0 + c1 + c2 + c3;
  tsum[tid] = ls;
  __syncthreads();
  for (int off = 1; off < 256; off <<= 1) {
    int t = (tid >= off) ? tsum[tid - off] : 0;
    __syncthreads();
    tsum[tid] += t;
    __syncthreads();
  }
  int ebase = tsum[tid] - ls;
  cnt[b0] = ebase;
  cnt[b0 + 1] = ebase + c0;
  cnt[b0 + 2] = ebase + c0 + c1;
  cnt[b0 + 3] = ebase + c0 + c1 + c2;
  __syncthreads();
  for (int i = tid; i < PSZ; i += 256) {
    int node = p * PSZ + i;
    if (node < NN) offsets[node] = gbase + cnt[i];
  }
  for (int i = tid; i < tot; i += 256) {
    int item = st[i];
    int dl = item & (PSZ - 1);
    int lp = atomicAdd(&cur[dl], 1);
    srcbuf[cnt[dl] + lp] = item >> 10;
  }
  __syncthreads();
  for (int i = tid; i < tot; i += 256) csr_src[gbase + i] = srcbuf[i];
}

// ---------------- Aggregation 1 (+b1): aggb[n] = bf16(sum h1[src] + b1) ----
// r12 proven form: 2 edges per wave-instruction via halves, uint2 loads.
__global__ __launch_bounds__(256) void k_agg1(const ushort* __restrict__ h1b,
                                              const int* __restrict__ offsets,
                                              const int* __restrict__ csr_src,
                                              const float* __restrict__ b1,
                                              ushort* __restrict__ aggb) {
  int w = threadIdx.x >> 6, lane = threadIdx.x & 63;
  int n = blockIdx.x * 4 + w;
  if (n >= NN) return;
  int beg = offsets[n], end = offsets[n + 1];
  int half = lane >> 5, ch = lane & 31;
  const uint2* h = (const uint2*)h1b;  // 32 uint2 per row (128 bf16)
  float4 a = {0.f, 0.f, 0.f, 0.f}, a2 = {0.f, 0.f, 0.f, 0.f};
  int i = beg + half;
  for (; i + 2 < end; i += 4) {
    uint2 v0 = h[(size_t)csr_src[i] * 32 + ch];
    uint2 v1 = h[(size_t)csr_src[i + 2] * 32 + ch];
    a.x += bflo(v0.x); a.y += bfhi(v0.x); a.z += bflo(v0.y); a.w += bfhi(v0.y);
    a2.x += bflo(v1.x); a2.y += bfhi(v1.x); a2.z += bflo(v1.y); a2.w += bfhi(v1.y);
  }
  if (i < end) {
    uint2 v = h[(size_t)csr_src[i] * 32 + ch];
    a.x += bflo(v.x); a.y += bfhi(v.x); a.z += bflo(v.y); a.w += bfhi(v.y);
  }
  a.x += a2.x; a.y += a2.y; a.z += a2.z; a.w += a2.w;
  a.x += __shfl_xor(a.x, 32);
  a.y += __shfl_xor(a.y, 32);
  a.z += __shfl_xor(a.z, 32);
  a.w += __shfl_xor(a.w, 32);
  if (half == 0) {
    float4 b = *(const float4*)(b1 + 4 * ch);
    uint2 o;
    o.x = packbf(a.x + b.x, a.y + b.y);
    o.y = packbf(a.z + b.z, a.w + b.w);
    ((uint2*)aggb)[(size_t)n * 32 + ch] = o;
  }
}

// ---------------- BN stats (bf16 input) ------------------------------------
__global__ __launch_bounds__(256) void k_bnstats(const ushort* __restrict__ aggb,
                                                 float* __restrict__ gsum,
                                                 float* __restrict__ gsq) {
  __shared__ float2 ss[4][64], qq[4][64];
  int tid = threadIdx.x;
  int lane = tid & 63, g = tid >> 6;
  int r0 = blockIdx.x * 128;
  const uint* a = (const uint*)aggb;
  float2 s = {0.f, 0.f}, q = {0.f, 0.f};
  for (int k = 0; k < 32; ++k) {
    int r = r0 + g + 4 * k;
    if (r < NN) {
      uint v = a[(size_t)r * 64 + lane];
      float lo = bflo(v), hi = bfhi(v);
      s.x += lo; s.y += hi;
      q.x += lo * lo; q.y += hi * hi;
    }
  }
  ss[g][lane] = s; qq[g][lane] = q;
  __syncthreads();
  if (g == 0) {
    float2 S = ss[0][lane], Q = qq[0][lane];
#pragma unroll
    for (int gg = 1; gg < 4; ++gg) {
      S.x += ss[gg][lane].x; S.y += ss[gg][lane].y;
      Q.x += qq[gg][lane].x; Q.y += qq[gg][lane].y;
    }
    atomicAdd(&gsum[2 * lane], S.x);
    atomicAdd(&gsum[2 * lane + 1], S.y);
    atomicAdd(&gsq[2 * lane], Q.x);
    atomicAdd(&gsq[2 * lane + 1], Q.y);
  }
}

// ---------------- GEMM2 via MFMA (BN-finalize fused in-block) ---------------
__global__ __launch_bounds__(256) void k_gemm2m(const ushort* __restrict__ aggb,
                                                const ushort* __restrict__ W2th,
                                                const ushort* __restrict__ W2tl,
                                                const float* __restrict__ gsum,
                                                const float* __restrict__ gsq,
                                                const float* __restrict__ gamma,
                                                const float* __restrict__ beta,
                                                ushort* __restrict__ h2b) {
  __shared__ __align__(16) ushort smem[27648]; // Bh 8704 | Bl 8704 | Adbuf 10240
  __shared__ float isgS[128], bbS[128];
  ushort* sBh = smem;            // [64][136]
  ushort* sBl = smem + 8704;     // [64][136]
  ushort* sA  = smem + 17408;    // 2 x [128][40]
  ushort* sOut = sA;             // epilogue alias: [128][72]
  const int tid = threadIdx.x;
  const int lane = tid & 63, wid = tid >> 6;
  const int wr = wid >> 1, wc = wid & 1;
  const int lrow = lane & 15, lkg = lane >> 4;
  const int row0 = blockIdx.x * 128;

  if (tid < 128) {  // fused bnfin (redundant per block, trivial)
    float mean = gsum[tid] * (1.f / NN);
    float var = fmaxf(gsq[tid] * (1.f / NN) - mean * mean, 0.f);
    float inv = 1.f / sqrtf(var + BN_EPS);
    float g = gamma[tid] * inv;
    isgS[tid] = g;
    bbS[tid] = beta[tid] - mean * g;
  }
#pragma unroll
  for (int i = 0; i < 4; ++i) {
    int c = i * 256 + tid;
    int n = c >> 4, kq = c & 15;
    *(uint4*)&sBh[n * 136 + kq * 8] = *(const uint4*)(W2th + (size_t)n * HID + kq * 8);
    *(uint4*)&sBl[n * 136 + kq * 8] = *(const uint4*)(W2tl + (size_t)n * HID + kq * 8);
  }

  f32x4 acc[4][2];
#pragma unroll
  for (int m = 0; m < 4; ++m)
#pragma unroll
    for (int n = 0; n < 2; ++n) acc[m][n] = (f32x4){0.f, 0.f, 0.f, 0.f};

  uint4 rA[2];
#pragma unroll
  for (int i = 0; i < 2; ++i) {
    int c = i * 256 + tid;
    int r = c >> 2, cq = c & 3;
    int grow = row0 + r; if (grow > NN - 1) grow = NN - 1;
    rA[i] = *(const uint4*)(aggb + (size_t)grow * HID + cq * 8);
  }
  __syncthreads();  // isgS/bbS + B visible

  {
    ushort* dA = sA;
#pragma unroll
    for (int i = 0; i < 2; ++i) {
      int c = i * 256 + tid;
      int r = c >> 2, cq = c & 3;
      int k0 = cq * 8;
      uint4 v = rA[i];
      uint o[4];
      const uint* vv = (const uint*)&v;
#pragma unroll
      for (int j = 0; j < 4; ++j) {
        float lo = bflo(vv[j]), hi = bfhi(vv[j]);
        lo = fmaxf(fmaf(lo, isgS[k0 + 2 * j], bbS[k0 + 2 * j]), 0.f);
        hi = fmaxf(fmaf(hi, isgS[k0 + 2 * j + 1], bbS[k0 + 2 * j + 1]), 0.f);
        o[j] = packbf(lo, hi);
      }
      *(uint4*)&dA[r * 40 + cq * 8] = *(const uint4*)o;
    }
  }

  int cur = 0;
  for (int s = 0; s < 4; ++s) {
    __syncthreads();
    const int kt = s * 32;
    if (s < 3) {
      int ktn = kt + 32;
#pragma unroll
      for (int i = 0; i < 2; ++i) {
        int c = i * 256 + tid;
        int r = c >> 2, cq = c & 3;
        int grow = row0 + r; if (grow > NN - 1) grow = NN - 1;
        rA[i] = *(const uint4*)(aggb + (size_t)grow * HID + ktn + cq * 8);
      }
    }
    {
      const ushort* bA = sA + cur * 5120;
      short8v ah[4], bh[2], bl[2];
#pragma unroll
      for (int m = 0; m < 4; ++m) {
        int r = wr * 64 + m * 16 + lrow;
        ah[m] = *(const short8v*)&bA[r * 40 + lkg * 8];
      }
#pragma unroll
      for (int n = 0; n < 2; ++n) {
        int c = wc * 32 + n * 16 + lrow;
        bh[n] = *(const short8v*)&sBh[c * 136 + kt + lkg * 8];
        bl[n] = *(const short8v*)&sBl[c * 136 + kt + lkg * 8];
      }
#pragma unroll
      for (int m = 0; m < 4; ++m)
#pragma unroll
        for (int n = 0; n < 2; ++n) {
          acc[m][n] = __builtin_amdgcn_mfma_f32_16x16x32_bf16(ah[m], bh[n], acc[m][n], 0, 0, 0);
          acc[m][n] = __builtin_amdgcn_mfma_f32_16x16x32_bf16(ah[m], bl[n], acc[m][n], 0, 0, 0);
        }
    }
    if (s < 3) {
      ushort* dA = sA + (cur ^ 1) * 5120;
      int k0b = (s + 1) * 32;
#pragma unroll
      for (int i = 0; i < 2; ++i) {
        int c = i * 256 + tid;
        int r = c >> 2, cq = c & 3;
        int k0 = k0b + cq * 8;
        uint4 v = rA[i];
        uint o[4];
        const uint* vv = (const uint*)&v;
#pragma unroll
        for (int j = 0; j < 4; ++j) {
          float lo = bflo(vv[j]), hi = bfhi(vv[j]);
          lo = fmaxf(fmaf(lo, isgS[k0 + 2 * j], bbS[k0 + 2 * j]), 0.f);
          hi = fmaxf(fmaf(hi, isgS[k0 + 2 * j + 1], bbS[k0 + 2 * j + 1]), 0.f);
          o[j] = packbf(lo, hi);
        }
        *(uint4*)&dA[r * 40 + cq * 8] = *(const uint4*)o;
      }
    }
    cur ^= 1;
  }

  __syncthreads();
#pragma unroll
  for (int m = 0; m < 4; ++m)
#pragma unroll
    for (int i = 0; i < 4; ++i) {
      int lr = wr * 64 + m * 16 + lkg * 4 + i;
#pragma unroll
      for (int n = 0; n < 2; ++n)
        sOut[lr * 72 + wc * 32 + n * 16 + lrow] = f2bf_n(acc[m][n][i]);
    }
  __syncthreads();
#pragma unroll
  for (int i = 0; i < 4; ++i) {
    int c = i * 256 + tid;
    int r = c >> 3, cq = c & 7;
    int grow = row0 + r;
    if (grow < NN)
      *(uint4*)(h2b + (size_t)grow * OUTD + cq * 8) =
          *(const uint4*)&sOut[r * 72 + cq * 8];
  }
}

// ---------------- Agg2 + b2 + L2 normalize + fp32 store ---------------------
__global__ __launch_bounds__(256) void k_agg2norm(const ushort* __restrict__ h2b,
                                                  const int* __restrict__ offsets,
                                                  const int* __restrict__ csr_src,
                                                  const float* __restrict__ b2,
                                                  float* __restrict__ out) {
  int w = threadIdx.x >> 6, lane = threadIdx.x & 63;
  int n = blockIdx.x * 4 + w;
  if (n >= NN) return;
  int beg = offsets[n], end = offsets[n + 1];
  int half = lane >> 5, ch = lane & 31;
  const uint* h = (const uint*)h2b;  // 32 uints per row (64 bf16)
  float2 a = {0.f, 0.f}, a2 = {0.f, 0.f};
  int i = beg + half;
  for (; i + 2 < end; i += 4) {
    uint v0 = h[(size_t)csr_src[i] * 32 + ch];
    uint v1 = h[(size_t)csr_src[i + 2] * 32 + ch];
    a.x += bflo(v0); a.y += bfhi(v0);
    a2.x += bflo(v1); a2.y += bfhi(v1);
  }
  if (i < end) {
    uint v = h[(size_t)csr_src[i] * 32 + ch];
    a.x += bflo(v); a.y += bfhi(v);
  }
  a.x += a2.x; a.y += a2.y;
  a.x += __shfl_xor(a.x, 32);
  a.y += __shfl_xor(a.y, 32);
  float2 b = *(const float2*)(b2 + 2 * ch);
  a.x += b.x; a.y += b.y;
  float q = a.x * a.x + a.y * a.y;
#pragma unroll
  for (int off = 16; off > 0; off >>= 1) q += __shfl_xor(q, off);
  float norm = sqrtf(q);
  float scale = 1.f / fmaxf(norm, 1e-12f);
  if (half == 0) {
    float2 o = {a.x * scale, a.y * scale};
    *(float2*)(out + (size_t)n * OUTD + 2 * ch) = o;
  }
}

// ---------------- launch ----------------------------------------------------
extern "C" void kernel_launch(void* const* d_in, const int* in_sizes, int n_in,
                              void* d_out, int out_size, void* d_ws, size_t ws_size,
                              hipStream_t stream) {
  const float* x     = (const float*)d_in[0];
  const int*   edges = (const int*)d_in[1];
  const float* W1    = (const float*)d_in[2];
  const float* b1    = (const float*)d_in[3];
  const float* W2    = (const float*)d_in[4];
  const float* b2    = (const float*)d_in[5];
  const float* gamma = (const float*)d_in[6];
  const float* beta  = (const float*)d_in[7];

  char* ws = (char*)d_ws;
  ushort* h1b     = (ushort*)(ws);                // 25.6 MB
  ushort* aggb    = (ushort*)(ws + 26000000);     // 25.6 MB (bf16)
  int*    csr_src = (int*)(ws + 77500000);        // 6.4 MB
  int*    offsets = (int*)(ws + 84000000);        // 100001 ints
  int*    staging = (int*)(ws + 84400128);        // 98*20480*4 = 8,028,160 B
  int*    gCursor = (int*)(ws + 92428544);        // 98 ints
  float*  gsum    = (float*)(ws + 92429568);      // 128 f
  float*  gsq     = (float*)(ws + 92430080);      // 128 f
  int*    eflag   = (int*)(ws + 92431616);        // 1 int
  ushort* Wth     = (ushort*)(ws + 92432128);     // 128 KB
  ushort* Wtl     = (ushort*)(ws + 92563200);     // 128 KB
  ushort* W2th    = (ushort*)(ws + 92694272);     // 16 KB
  ushort* W2tl    = (ushort*)(ws + 92710656);     // 16 KB
  ushort* h2b     = h1b;                          // reuse (h1b dead after agg1)

  if (ws_size < 92727040) return;  // scratch layout requirement

  // zero gCursor + gsum + gsq (2 KB)
  hipMemsetAsync(gCursor, 0, 2048, stream);

  k_prep<<<289, 256, 0, stream>>>(edges, W1, W2, eflag, Wth, Wtl, W2th, W2tl);
  k_fused1<<<NBIN + 782, 256, 0, stream>>>(x, Wth, Wtl, edges, eflag,
                                           gCursor, staging, h1b);
  k_csrpart<<<NP, 256, 0, stream>>>(staging, gCursor, offsets, csr_src);
  k_agg1<<<25000, 256, 0, stream>>>(h1b, offsets, csr_src, b1, aggb);
  k_bnstats<<<782, 256, 0, stream>>>(aggb, gsum, gsq);
  k_gemm2m<<<782, 256, 0, stream>>>(aggb, W2th, W2tl, gsum, gsq, gamma, beta, h2b);
  k_agg2norm<<<25000, 256, 0, stream>>>(h2b, offsets, csr_src, b2,
                                        (float*)d_out);
}

// Round 15
// 297.262 us; speedup vs baseline: 1.1266x; 1.0327x over previous
//
#include <hip/hip_runtime.h>
#include <hip/hip_bf16.h>
#include <stdint.h>

#define NN 100000
#define NE 1600000
#define IND 512
#define HID 128
#define OUTD 64
#define BN_EPS 1e-5f
#define NP 98        // ceil(NN/1024) dst partitions
#define PSZ 1024     // nodes per partition
#define PCAP 20480   // staging capacity per partition
#define BINCH 8192   // edges per bin block
#define NBIN 196     // ceil(NE/BINCH)

typedef __attribute__((ext_vector_type(8))) short short8v;
typedef __attribute__((ext_vector_type(4))) float f32x4;

// ---- fp32 -> bf16 (RNE) ----------------------------------------------------
__device__ __forceinline__ ushort f2bf(float f, float& back) {
  uint u = __float_as_uint(f);
  uint r = u + 0x7FFFu + ((u >> 16) & 1u);
  ushort h = (ushort)(r >> 16);
  back = __uint_as_float(((uint)h) << 16);
  return h;
}
__device__ __forceinline__ ushort f2bf_n(float f) {
  uint u = __float_as_uint(f);
  uint r = u + 0x7FFFu + ((u >> 16) & 1u);
  return (ushort)(r >> 16);
}
__device__ __forceinline__ float bf2f(ushort h) {
  return __uint_as_float(((uint)h) << 16);
}
__device__ __forceinline__ float bflo(uint v) { return __uint_as_float(v << 16); }
__device__ __forceinline__ float bfhi(uint v) { return __uint_as_float(v & 0xffff0000u); }
__device__ __forceinline__ uint packbf(float lo, float hi) {
  return (uint)f2bf_n(lo) | ((uint)f2bf_n(hi) << 16);
}

__device__ __forceinline__ int edge_at(const int* e32, int f, int i) {
  if (f) return (int)((const long long*)e32)[i];
  return e32[i];
}

// ---------------- K0: detect + prepW(W1^T hi/lo) + prepW2(W2^T hi/lo) -------
__global__ __launch_bounds__(256) void k_prep(const int* __restrict__ edges,
                                              const float* __restrict__ W1,
                                              const float* __restrict__ W2,
                                              int* __restrict__ flag,
                                              ushort* __restrict__ Wth,
                                              ushort* __restrict__ Wtl,
                                              ushort* __restrict__ W2th,
                                              ushort* __restrict__ W2tl) {
  const int bid = blockIdx.x, tid = threadIdx.x;
  if (bid == 0) {
    __shared__ int nz;
    if (tid == 0) nz = 0;
    __syncthreads();
    if (tid < 64) {
      int v = edges[2 * tid + 1];
      if (v != 0) atomicAdd(&nz, 1);
    }
    __syncthreads();
    if (tid == 0) *flag = (nz == 0) ? 1 : 0;  // 1 => int64
    return;
  }
  if (bid <= 256) {  // W1^T: [n][k], 128*512
    int i = (bid - 1) * 256 + tid;
    int n = i >> 9, k = i & 511;
    float w = W1[(size_t)k * HID + n];
    float back;
    Wth[i] = f2bf(w, back);
    Wtl[i] = f2bf_n(w - back);
    return;
  }
  {  // W2^T: [n][k], 64*128
    int j = (bid - 257) * 256 + tid;
    int n = j >> 7, k = j & 127;
    float w = W2[(size_t)k * OUTD + n];
    float back;
    W2th[j] = f2bf(w, back);
    W2tl[j] = f2bf_n(w - back);
  }
}

// ---------------- K1 body A: CSR bin pass (blocks 0..195) -------------------
__device__ void bin_body(int bid, ushort* smem16, const int* edges,
                         const int* flag, int* gCursor, int* staging) {
  int* cnt   = (int*)smem16;        // [NP]
  int* scn   = cnt + 128;           // [NP]
  int* base  = cnt + 256;           // [NP]
  int* cur   = cnt + 384;           // [NP]
  int* items = cnt + 512;           // [BINCH]
  const int tid = threadIdx.x;
  const int e0 = bid * BINCH;
  const int ecnt = min(BINCH, NE - e0);
  const int f = *flag;
  for (int i = tid; i < NP; i += 256) cnt[i] = 0;
  __syncthreads();
  for (int i = tid; i < ecnt; i += 256) {
    int d = edge_at(edges, f, NE + e0 + i);
    atomicAdd(&cnt[d >> 10], 1);
  }
  __syncthreads();
  if (tid == 0) {
    int s = 0;
    for (int p = 0; p < NP; ++p) { scn[p] = s; s += cnt[p]; }
  }
  __syncthreads();
  if (tid < NP) {
    base[tid] = (cnt[tid] > 0) ? atomicAdd(&gCursor[tid], cnt[tid]) : 0;
    cur[tid] = 0;
  }
  __syncthreads();
  for (int i = tid; i < ecnt; i += 256) {
    int d = edge_at(edges, f, NE + e0 + i);
    int s = edge_at(edges, f, e0 + i);
    int p = d >> 10;
    int lp = atomicAdd(&cur[p], 1);
    items[scn[p] + lp] = (s << 10) | (d & (PSZ - 1));
  }
  __syncthreads();
  for (int p = 0; p < NP; ++p) {
    int c = cnt[p];
    if (c == 0) continue;
    int gb = base[p];
    int* dst = staging + (size_t)p * PCAP;
    for (int i = tid; i < c; i += 256) {
      int gpos = gb + i;
      if (gpos < PCAP) dst[gpos] = items[scn[p] + i];
    }
  }
}

// ---------------- K1 body B: GEMM1, depth-2 A pipeline ----------------------
__device__ __forceinline__ void g1_loadA(const float* x, int row0, int tid,
                                         int kt, float4 ra[4]) {
#pragma unroll
  for (int i = 0; i < 4; ++i) {
    int flat = i * 256 + tid, r = flat >> 3, kq = flat & 7;
    int grow = row0 + r; if (grow > NN - 1) grow = NN - 1;
    ra[i] = *(const float4*)(x + (size_t)grow * IND + kt + kq * 4);
  }
}
__device__ __forceinline__ void g1_loadB(const ushort* Wth, const ushort* Wtl,
                                         int tid, int kt, uint4 rbh[2], uint4 rbl[2]) {
#pragma unroll
  for (int i = 0; i < 2; ++i) {
    int flat = i * 256 + tid, col = flat >> 2, kc = flat & 3;
    rbh[i] = *(const uint4*)(Wth + (size_t)col * IND + kt + kc * 8);
    rbl[i] = *(const uint4*)(Wtl + (size_t)col * IND + kt + kc * 8);
  }
}
__device__ __forceinline__ void g1_storeA(ushort* dAh, int tid, const float4 ra[4]) {
#pragma unroll
  for (int i = 0; i < 4; ++i) {
    int flat = i * 256 + tid, r = flat >> 3, kq = flat & 7;
    ushort4 hi;
    hi.x = f2bf_n(ra[i].x); hi.y = f2bf_n(ra[i].y);
    hi.z = f2bf_n(ra[i].z); hi.w = f2bf_n(ra[i].w);
    *(ushort4*)&dAh[r * 40 + kq * 4] = hi;
  }
}
__device__ __forceinline__ void g1_storeB(ushort* dBh, ushort* dBl, int tid,
                                          const uint4 rbh[2], const uint4 rbl[2]) {
#pragma unroll
  for (int i = 0; i < 2; ++i) {
    int flat = i * 256 + tid, col = flat >> 2, kc = flat & 3;
    *(uint4*)&dBh[col * 40 + kc * 8] = rbh[i];
    *(uint4*)&dBl[col * 40 + kc * 8] = rbl[i];
  }
}
__device__ __forceinline__ void g1_mfma(const ushort* buf, int wr, int wc,
                                        int lrow, int lkg, f32x4 acc[4][4]) {
  const ushort* bAh = buf;
  const ushort* bBh = buf + 5120;
  const ushort* bBl = buf + 10240;
  short8v ah[4], bh[4], bl[4];
#pragma unroll
  for (int m = 0; m < 4; ++m) {
    int r = wr * 64 + m * 16 + lrow;
    ah[m] = *(const short8v*)&bAh[r * 40 + lkg * 8];
  }
#pragma unroll
  for (int n = 0; n < 4; ++n) {
    int c = wc * 64 + n * 16 + lrow;
    bh[n] = *(const short8v*)&bBh[c * 40 + lkg * 8];
    bl[n] = *(const short8v*)&bBl[c * 40 + lkg * 8];
  }
#pragma unroll
  for (int m = 0; m < 4; ++m)
#pragma unroll
    for (int n = 0; n < 4; ++n) {
      acc[m][n] = __builtin_amdgcn_mfma_f32_16x16x32_bf16(ah[m], bh[n], acc[m][n], 0, 0, 0);
      acc[m][n] = __builtin_amdgcn_mfma_f32_16x16x32_bf16(ah[m], bl[n], acc[m][n], 0, 0, 0);
    }
}
__device__ __forceinline__ void g1_barrier() {
  asm volatile("s_waitcnt lgkmcnt(0)");
  __builtin_amdgcn_sched_barrier(0);
  __builtin_amdgcn_s_barrier();
  __builtin_amdgcn_sched_barrier(0);
}

__device__ void gemm1_body(int bid, ushort* smem, const float* x,
                           const ushort* Wth, const ushort* Wtl,
                           ushort* h1b) {
  ushort* sOut = smem;
  const int tid = threadIdx.x;
  const int lane = tid & 63, wid = tid >> 6;
  const int wr = wid >> 1, wc = wid & 1;
  const int lrow = lane & 15, lkg = lane >> 4;
  const int row0 = bid * 128;
  ushort* B0 = smem;            // buffer 0: Ah | Bh | Bl (15360 u16)
  ushort* B1 = smem + 15360;    // buffer 1

  f32x4 acc[4][4];
#pragma unroll
  for (int m = 0; m < 4; ++m)
#pragma unroll
    for (int n = 0; n < 4; ++n) acc[m][n] = (f32x4){0.f, 0.f, 0.f, 0.f};

  float4 raA0[4], raA1[4];
  uint4 rbh[2], rbl[2];

  g1_loadA(x, row0, tid, 0, raA0);
  g1_loadA(x, row0, tid, 32, raA1);
  g1_loadB(Wth, Wtl, tid, 0, rbh, rbl);
  g1_storeA(B0, tid, raA0);
  g1_storeB(B0 + 5120, B0 + 10240, tid, rbh, rbl);
  g1_barrier();

  for (int ss = 0; ss < 8; ++ss) {
    int s0 = 2 * ss;
    if (s0 + 2 < 16) g1_loadA(x, row0, tid, (s0 + 2) * 32, raA0);
    g1_loadB(Wth, Wtl, tid, (s0 + 1) * 32, rbh, rbl);
    g1_mfma(B0, wr, wc, lrow, lkg, acc);
    g1_storeA(B1, tid, raA1);
    g1_storeB(B1 + 5120, B1 + 10240, tid, rbh, rbl);
    g1_barrier();

    int s1 = s0 + 1;
    if (s1 + 2 < 16) {
      g1_loadA(x, row0, tid, (s1 + 2) * 32, raA1);
    }
    if (s1 + 1 < 16) {
      g1_loadB(Wth, Wtl, tid, (s1 + 1) * 32, rbh, rbl);
    }
    g1_mfma(B1, wr, wc, lrow, lkg, acc);
    if (s1 + 1 < 16) {
      g1_storeA(B0, tid, raA0);
      g1_storeB(B0 + 5120, B0 + 10240, tid, rbh, rbl);
      g1_barrier();
    }
  }

  __syncthreads();
#pragma unroll
  for (int m = 0; m < 4; ++m)
#pragma unroll
    for (int i = 0; i < 4; ++i) {
      int lr = wr * 64 + m * 16 + lkg * 4 + i;
#pragma unroll
      for (int n = 0; n < 4; ++n)
        sOut[lr * 136 + wc * 64 + n * 16 + lrow] = f2bf_n(acc[m][n][i]);
    }
  __syncthreads();
#pragma unroll
  for (int j = 0; j < 8; ++j) {
    int flat = j * 256 + tid;
    int r = flat >> 4, c = flat & 15;
    int grow = row0 + r;
    if (grow < NN)
      *(uint4*)(h1b + (size_t)grow * HID + c * 8) =
          *(const uint4*)&sOut[r * 136 + c * 8];
  }
}

// ---------------- K1: fused bin (first) + gemm1 -----------------------------
__global__ __launch_bounds__(256) void k_fused1(const float* __restrict__ x,
                                                const ushort* __restrict__ Wth,
                                                const ushort* __restrict__ Wtl,
                                                const int* __restrict__ edges,
                                                const int* __restrict__ flag,
                                                int* __restrict__ gCursor,
                                                int* __restrict__ staging,
                                                ushort* __restrict__ h1b) {
  __shared__ __align__(16) ushort smem[30720];
  if (blockIdx.x < NBIN)
    bin_body(blockIdx.x, smem, edges, flag, gCursor, staging);
  else
    gemm1_body(blockIdx.x - NBIN, smem, x, Wth, Wtl, h1b);
}

// ---------------- CSR pass 2: per-partition counting sort (self-scanned) ----
__global__ __launch_bounds__(256) void k_csrpart(const int* __restrict__ staging,
                                                 const int* __restrict__ gCursor,
                                                 int* __restrict__ offsets,
                                                 int* __restrict__ csr_src) {
  __shared__ int cnt[PSZ];
  __shared__ int cur[PSZ];
  __shared__ int tsum[256];
  __shared__ int srcbuf[PCAP];   // 80 KB
  __shared__ int gbase_s;
  const int tid = threadIdx.x;
  const int p = blockIdx.x;
  if (tid == 0) {
    int s = 0;
    for (int q = 0; q < p; ++q) s += min(gCursor[q], PCAP);
    gbase_s = s;
    if (p == NP - 1) offsets[NN] = NE;
  }
  const int tot = min(gCursor[p], PCAP);
  const int* st = staging + (size_t)p * PCAP;
  for (int i = tid; i < PSZ; i += 256) { cnt[i] = 0; cur[i] = 0; }
  __syncthreads();
  const int gbase = gbase_s;
  for (int i = tid; i < tot; i += 256) atomicAdd(&cnt[st[i] & (PSZ - 1)], 1);
  __syncthreads();
  int b0 = tid * 4;
  int c0 = cnt[b0], c1 = cnt[b0 + 1], c2 = cnt[b0 + 2], c3 = cnt[b0 + 3];
  int ls = c0 + c1 + c2 + c3;
  tsum[tid] = ls;
  __syncthreads();
  for (int off = 1; off < 256; off <<= 1) {
    int t = (tid >= off) ? tsum[tid - off] : 0;
    __syncthreads();
    tsum[tid] += t;
    __syncthreads();
  }
  int ebase = tsum[tid] - ls;
  cnt[b0] = ebase;
  cnt[b0 + 1] = ebase + c0;
  cnt[b0 + 2] = ebase + c0 + c1;
  cnt[b0 + 3] = ebase + c0 + c1 + c2;
  __syncthreads();
  for (int i = tid; i < PSZ; i += 256) {
    int node = p * PSZ + i;
    if (node < NN) offsets[node] = gbase + cnt[i];
  }
  for (int i = tid; i < tot; i += 256) {
    int item = st[i];
    int dl = item & (PSZ - 1);
    int lp = atomicAdd(&cur[dl], 1);
    srcbuf[cnt[dl] + lp] = item >> 10;
  }
  __syncthreads();
  for (int i = tid; i < tot; i += 256) csr_src[gbase + i] = srcbuf[i];
}

// ---------------- Aggregation 1 (+b1): 8 edges in flight per wave -----------
// Halves take even/odd CSR slots; 4 independent accumulator chains give 4
// outstanding gather instructions (was 2 -> latency-bound at ~1.4 TB/s).
__global__ __launch_bounds__(256) void k_agg1(const ushort* __restrict__ h1b,
                                              const int* __restrict__ offsets,
                                              const int* __restrict__ csr_src,
                                              const float* __restrict__ b1,
                                              ushort* __restrict__ aggb) {
  int w = threadIdx.x >> 6, lane = threadIdx.x & 63;
  int n = blockIdx.x * 4 + w;
  if (n >= NN) return;
  int beg = offsets[n], end = offsets[n + 1];
  int half = lane >> 5, ch = lane & 31;
  const uint2* h = (const uint2*)h1b;  // 32 uint2 per row (128 bf16)
  float4 a = {0.f, 0.f, 0.f, 0.f}, a2 = {0.f, 0.f, 0.f, 0.f};
  float4 a3 = {0.f, 0.f, 0.f, 0.f}, a4 = {0.f, 0.f, 0.f, 0.f};
  int i = beg + half;
  for (; i + 6 < end; i += 8) {
    uint2 v0 = h[(size_t)csr_src[i] * 32 + ch];
    uint2 v1 = h[(size_t)csr_src[i + 2] * 32 + ch];
    uint2 v2 = h[(size_t)csr_src[i + 4] * 32 + ch];
    uint2 v3 = h[(size_t)csr_src[i + 6] * 32 + ch];
    a.x += bflo(v0.x); a.y += bfhi(v0.x); a.z += bflo(v0.y); a.w += bfhi(v0.y);
    a2.x += bflo(v1.x); a2.y += bfhi(v1.x); a2.z += bflo(v1.y); a2.w += bfhi(v1.y);
    a3.x += bflo(v2.x); a3.y += bfhi(v2.x); a3.z += bflo(v2.y); a3.w += bfhi(v2.y);
    a4.x += bflo(v3.x); a4.y += bfhi(v3.x); a4.z += bflo(v3.y); a4.w += bfhi(v3.y);
  }
  for (; i + 2 < end; i += 4) {
    uint2 v0 = h[(size_t)csr_src[i] * 32 + ch];
    uint2 v1 = h[(size_t)csr_src[i + 2] * 32 + ch];
    a.x += bflo(v0.x); a.y += bfhi(v0.x); a.z += bflo(v0.y); a.w += bfhi(v0.y);
    a2.x += bflo(v1.x); a2.y += bfhi(v1.x); a2.z += bflo(v1.y); a2.w += bfhi(v1.y);
  }
  if (i < end) {
    uint2 v = h[(size_t)csr_src[i] * 32 + ch];
    a.x += bflo(v.x); a.y += bfhi(v.x); a.z += bflo(v.y); a.w += bfhi(v.y);
  }
  a.x += a2.x + a3.x + a4.x;
  a.y += a2.y + a3.y + a4.y;
  a.z += a2.z + a3.z + a4.z;
  a.w += a2.w + a3.w + a4.w;
  a.x += __shfl_xor(a.x, 32);
  a.y += __shfl_xor(a.y, 32);
  a.z += __shfl_xor(a.z, 32);
  a.w += __shfl_xor(a.w, 32);
  if (half == 0) {
    float4 b = *(const float4*)(b1 + 4 * ch);
    uint2 o;
    o.x = packbf(a.x + b.x, a.y + b.y);
    o.y = packbf(a.z + b.z, a.w + b.w);
    ((uint2*)aggb)[(size_t)n * 32 + ch] = o;
  }
}

// ---------------- BN stats (bf16 input) ------------------------------------
__global__ __launch_bounds__(256) void k_bnstats(const ushort* __restrict__ aggb,
                                                 float* __restrict__ gsum,
                                                 float* __restrict__ gsq) {
  __shared__ float2 ss[4][64], qq[4][64];
  int tid = threadIdx.x;
  int lane = tid & 63, g = tid >> 6;
  int r0 = blockIdx.x * 128;
  const uint* a = (const uint*)aggb;
  float2 s = {0.f, 0.f}, q = {0.f, 0.f};
  for (int k = 0; k < 32; ++k) {
    int r = r0 + g + 4 * k;
    if (r < NN) {
      uint v = a[(size_t)r * 64 + lane];
      float lo = bflo(v), hi = bfhi(v);
      s.x += lo; s.y += hi;
      q.x += lo * lo; q.y += hi * hi;
    }
  }
  ss[g][lane] = s; qq[g][lane] = q;
  __syncthreads();
  if (g == 0) {
    float2 S = ss[0][lane], Q = qq[0][lane];
#pragma unroll
    for (int gg = 1; gg < 4; ++gg) {
      S.x += ss[gg][lane].x; S.y += ss[gg][lane].y;
      Q.x += qq[gg][lane].x; Q.y += qq[gg][lane].y;
    }
    atomicAdd(&gsum[2 * lane], S.x);
    atomicAdd(&gsum[2 * lane + 1], S.y);
    atomicAdd(&gsq[2 * lane], Q.x);
    atomicAdd(&gsq[2 * lane + 1], Q.y);
  }
}

// ---------------- GEMM2 via MFMA (BN-finalize fused in-block) ---------------
__global__ __launch_bounds__(256) void k_gemm2m(const ushort* __restrict__ aggb,
                                                const ushort* __restrict__ W2th,
                                                const ushort* __restrict__ W2tl,
                                                const float* __restrict__ gsum,
                                                const float* __restrict__ gsq,
                                                const float* __restrict__ gamma,
                                                const float* __restrict__ beta,
                                                ushort* __restrict__ h2b) {
  __shared__ __align__(16) ushort smem[27648]; // Bh 8704 | Bl 8704 | Adbuf 10240
  __shared__ float isgS[128], bbS[128];
  ushort* sBh = smem;            // [64][136]
  ushort* sBl = smem + 8704;     // [64][136]
  ushort* sA  = smem + 17408;    // 2 x [128][40]
  ushort* sOut = sA;             // epilogue alias: [128][72]
  const int tid = threadIdx.x;
  const int lane = tid & 63, wid = tid >> 6;
  const int wr = wid >> 1, wc = wid & 1;
  const int lrow = lane & 15, lkg = lane >> 4;
  const int row0 = blockIdx.x * 128;

  if (tid < 128) {  // fused bnfin (redundant per block, trivial)
    float mean = gsum[tid] * (1.f / NN);
    float var = fmaxf(gsq[tid] * (1.f / NN) - mean * mean, 0.f);
    float inv = 1.f / sqrtf(var + BN_EPS);
    float g = gamma[tid] * inv;
    isgS[tid] = g;
    bbS[tid] = beta[tid] - mean * g;
  }
#pragma unroll
  for (int i = 0; i < 4; ++i) {
    int c = i * 256 + tid;
    int n = c >> 4, kq = c & 15;
    *(uint4*)&sBh[n * 136 + kq * 8] = *(const uint4*)(W2th + (size_t)n * HID + kq * 8);
    *(uint4*)&sBl[n * 136 + kq * 8] = *(const uint4*)(W2tl + (size_t)n * HID + kq * 8);
  }

  f32x4 acc[4][2];
#pragma unroll
  for (int m = 0; m < 4; ++m)
#pragma unroll
    for (int n = 0; n < 2; ++n) acc[m][n] = (f32x4){0.f, 0.f, 0.f, 0.f};

  uint4 rA[2];
#pragma unroll
  for (int i = 0; i < 2; ++i) {
    int c = i * 256 + tid;
    int r = c >> 2, cq = c & 3;
    int grow = row0 + r; if (grow > NN - 1) grow = NN - 1;
    rA[i] = *(const uint4*)(aggb + (size_t)grow * HID + cq * 8);
  }
  __syncthreads();  // isgS/bbS + B visible

  {
    ushort* dA = sA;
#pragma unroll
    for (int i = 0; i < 2; ++i) {
      int c = i * 256 + tid;
      int r = c >> 2, cq = c & 3;
      int k0 = cq * 8;
      uint4 v = rA[i];
      uint o[4];
      const uint* vv = (const uint*)&v;
#pragma unroll
      for (int j = 0; j < 4; ++j) {
        float lo = bflo(vv[j]), hi = bfhi(vv[j]);
        lo = fmaxf(fmaf(lo, isgS[k0 + 2 * j], bbS[k0 + 2 * j]), 0.f);
        hi = fmaxf(fmaf(hi, isgS[k0 + 2 * j + 1], bbS[k0 + 2 * j + 1]), 0.f);
        o[j] = packbf(lo, hi);
      }
      *(uint4*)&dA[r * 40 + cq * 8] = *(const uint4*)o;
    }
  }

  int cur = 0;
  for (int s = 0; s < 4; ++s) {
    __syncthreads();
    const int kt = s * 32;
    if (s < 3) {
      int ktn = kt + 32;
#pragma unroll
      for (int i = 0; i < 2; ++i) {
        int c = i * 256 + tid;
        int r = c >> 2, cq = c & 3;
        int grow = row0 + r; if (grow > NN - 1) grow = NN - 1;
        rA[i] = *(const uint4*)(aggb + (size_t)grow * HID + ktn + cq * 8);
      }
    }
    {
      const ushort* bA = sA + cur * 5120;
      short8v ah[4], bh[2], bl[2];
#pragma unroll
      for (int m = 0; m < 4; ++m) {
        int r = wr * 64 + m * 16 + lrow;
        ah[m] = *(const short8v*)&bA[r * 40 + lkg * 8];
      }
#pragma unroll
      for (int n = 0; n < 2; ++n) {
        int c = wc * 32 + n * 16 + lrow;
        bh[n] = *(const short8v*)&sBh[c * 136 + kt + lkg * 8];
        bl[n] = *(const short8v*)&sBl[c * 136 + kt + lkg * 8];
      }
#pragma unroll
      for (int m = 0; m < 4; ++m)
#pragma unroll
        for (int n = 0; n < 2; ++n) {
          acc[m][n] = __builtin_amdgcn_mfma_f32_16x16x32_bf16(ah[m], bh[n], acc[m][n], 0, 0, 0);
          acc[m][n] = __builtin_amdgcn_mfma_f32_16x16x32_bf16(ah[m], bl[n], acc[m][n], 0, 0, 0);
        }
    }
    if (s < 3) {
      ushort* dA = sA + (cur ^ 1) * 5120;
      int k0b = (s + 1) * 32;
#pragma unroll
      for (int i = 0; i < 2; ++i) {
        int c = i * 256 + tid;
        int r = c >> 2, cq = c & 3;
        int k0 = k0b + cq * 8;
        uint4 v = rA[i];
        uint o[4];
        const uint* vv = (const uint*)&v;
#pragma unroll
        for (int j = 0; j < 4; ++j) {
          float lo = bflo(vv[j]), hi = bfhi(vv[j]);
          lo = fmaxf(fmaf(lo, isgS[k0 + 2 * j], bbS[k0 + 2 * j]), 0.f);
          hi = fmaxf(fmaf(hi, isgS[k0 + 2 * j + 1], bbS[k0 + 2 * j + 1]), 0.f);
          o[j] = packbf(lo, hi);
        }
        *(uint4*)&dA[r * 40 + cq * 8] = *(const uint4*)o;
      }
    }
    cur ^= 1;
  }

  __syncthreads();
#pragma unroll
  for (int m = 0; m < 4; ++m)
#pragma unroll
    for (int i = 0; i < 4; ++i) {
      int lr = wr * 64 + m * 16 + lkg * 4 + i;
#pragma unroll
      for (int n = 0; n < 2; ++n)
        sOut[lr * 72 + wc * 32 + n * 16 + lrow] = f2bf_n(acc[m][n][i]);
    }
  __syncthreads();
#pragma unroll
  for (int i = 0; i < 4; ++i) {
    int c = i * 256 + tid;
    int r = c >> 3, cq = c & 7;
    int grow = row0 + r;
    if (grow < NN)
      *(uint4*)(h2b + (size_t)grow * OUTD + cq * 8) =
          *(const uint4*)&sOut[r * 72 + cq * 8];
  }
}

// ---------------- Agg2 + b2 + L2 normalize: 8 edges in flight ---------------
__global__ __launch_bounds__(256) void k_agg2norm(const ushort* __restrict__ h2b,
                                                  const int* __restrict__ offsets,
                                                  const int* __restrict__ csr_src,
                                                  const float* __restrict__ b2,
                                                  float* __restrict__ out) {
  int w = threadIdx.x >> 6, lane = threadIdx.x & 63;
  int n = blockIdx.x * 4 + w;
  if (n >= NN) return;
  int beg = offsets[n], end = offsets[n + 1];
  int half = lane >> 5, ch = lane & 31;
  const uint* h = (const uint*)h2b;  // 32 uints per row (64 bf16)
  float2 a = {0.f, 0.f}, a2 = {0.f, 0.f}, a3 = {0.f, 0.f}, a4 = {0.f, 0.f};
  int i = beg + half;
  for (; i + 6 < end; i += 8) {
    uint v0 = h[(size_t)csr_src[i] * 32 + ch];
    uint v1 = h[(size_t)csr_src[i + 2] * 32 + ch];
    uint v2 = h[(size_t)csr_src[i + 4] * 32 + ch];
    uint v3 = h[(size_t)csr_src[i + 6] * 32 + ch];
    a.x += bflo(v0); a.y += bfhi(v0);
    a2.x += bflo(v1); a2.y += bfhi(v1);
    a3.x += bflo(v2); a3.y += bfhi(v2);
    a4.x += bflo(v3); a4.y += bfhi(v3);
  }
  for (; i + 2 < end; i += 4) {
    uint v0 = h[(size_t)csr_src[i] * 32 + ch];
    uint v1 = h[(size_t)csr_src[i + 2] * 32 + ch];
    a.x += bflo(v0); a.y += bfhi(v0);
    a2.x += bflo(v1); a2.y += bfhi(v1);
  }
  if (i < end) {
    uint v = h[(size_t)csr_src[i] * 32 + ch];
    a.x += bflo(v); a.y += bfhi(v);
  }
  a.x += a2.x + a3.x + a4.x;
  a.y += a2.y + a3.y + a4.y;
  a.x += __shfl_xor(a.x, 32);
  a.y += __shfl_xor(a.y, 32);
  float2 b = *(const float2*)(b2 + 2 * ch);
  a.x += b.x; a.y += b.y;
  float q = a.x * a.x + a.y * a.y;
#pragma unroll
  for (int off = 16; off > 0; off >>= 1) q += __shfl_xor(q, off);
  float norm = sqrtf(q);
  float scale = 1.f / fmaxf(norm, 1e-12f);
  if (half == 0) {
    float2 o = {a.x * scale, a.y * scale};
    *(float2*)(out + (size_t)n * OUTD + 2 * ch) = o;
  }
}

// ---------------- launch ----------------------------------------------------
extern "C" void kernel_launch(void* const* d_in, const int* in_sizes, int n_in,
                              void* d_out, int out_size, void* d_ws, size_t ws_size,
                              hipStream_t stream) {
  const float* x     = (const float*)d_in[0];
  const int*   edges = (const int*)d_in[1];
  const float* W1    = (const float*)d_in[2];
  const float* b1    = (const float*)d_in[3];
  const float* W2    = (const float*)d_in[4];
  const float* b2    = (const float*)d_in[5];
  const float* gamma = (const float*)d_in[6];
  const float* beta  = (const float*)d_in[7];

  char* ws = (char*)d_ws;
  ushort* h1b     = (ushort*)(ws);                // 25.6 MB
  ushort* aggb    = (ushort*)(ws + 26000000);     // 25.6 MB (bf16)
  int*    csr_src = (int*)(ws + 77500000);        // 6.4 MB
  int*    offsets = (int*)(ws + 84000000);        // 100001 ints
  int*    staging = (int*)(ws + 84400128);        // 98*20480*4 = 8,028,160 B
  int*    gCursor = (int*)(ws + 92428544);        // 98 ints
  float*  gsum    = (float*)(ws + 92429568);      // 128 f
  float*  gsq     = (float*)(ws + 92430080);      // 128 f
  int*    eflag   = (int*)(ws + 92431616);        // 1 int
  ushort* Wth     = (ushort*)(ws + 92432128);     // 128 KB
  ushort* Wtl     = (ushort*)(ws + 92563200);     // 128 KB
  ushort* W2th    = (ushort*)(ws + 92694272);     // 16 KB
  ushort* W2tl    = (ushort*)(ws + 92710656);     // 16 KB
  ushort* h2b     = h1b;                          // reuse (h1b dead after agg1)

  if (ws_size < 92727040) return;  // scratch layout requirement

  // zero gCursor + gsum + gsq (2 KB)
  hipMemsetAsync(gCursor, 0, 2048, stream);

  k_prep<<<289, 256, 0, stream>>>(edges, W1, W2, eflag, Wth, Wtl, W2th, W2tl);
  k_fused1<<<NBIN + 782, 256, 0, stream>>>(x, Wth, Wtl, edges, eflag,
                                           gCursor, staging, h1b);
  k_csrpart<<<NP, 256, 0, stream>>>(staging, gCursor, offsets, csr_src);
  k_agg1<<<25000, 256, 0, stream>>>(h1b, offsets, csr_src, b1, aggb);
  k_bnstats<<<782, 256, 0, stream>>>(aggb, gsum, gsq);
  k_gemm2m<<<782, 256, 0, stream>>>(aggb, W2th, W2tl, gsum, gsq, gamma, beta, h2b);
  k_agg2norm<<<25000, 256, 0, stream>>>(h2b, offsets, csr_src, b2,
                                        (float*)d_out);
}

// Round 16
// 282.520 us; speedup vs baseline: 1.1853x; 1.0522x over previous
//
#include <hip/hip_runtime.h>
#include <hip/hip_bf16.h>
#include <stdint.h>

#define NN 100000
#define NE 1600000
#define IND 512
#define HID 128
#define OUTD 64
#define BN_EPS 1e-5f
#define NP 98        // ceil(NN/1024) dst partitions
#define PSZ 1024     // nodes per partition
#define PCAP 20480   // staging capacity per partition
#define BINCH 8192   // edges per bin block
#define NBIN 196     // ceil(NE/BINCH)

typedef __attribute__((ext_vector_type(8))) short short8v;
typedef __attribute__((ext_vector_type(4))) float f32x4;

// ---- fp32 -> bf16 (RNE) ----------------------------------------------------
__device__ __forceinline__ ushort f2bf(float f, float& back) {
  uint u = __float_as_uint(f);
  uint r = u + 0x7FFFu + ((u >> 16) & 1u);
  ushort h = (ushort)(r >> 16);
  back = __uint_as_float(((uint)h) << 16);
  return h;
}
__device__ __forceinline__ ushort f2bf_n(float f) {
  uint u = __float_as_uint(f);
  uint r = u + 0x7FFFu + ((u >> 16) & 1u);
  return (ushort)(r >> 16);
}
__device__ __forceinline__ float bf2f(ushort h) {
  return __uint_as_float(((uint)h) << 16);
}
__device__ __forceinline__ float bflo(uint v) { return __uint_as_float(v << 16); }
__device__ __forceinline__ float bfhi(uint v) { return __uint_as_float(v & 0xffff0000u); }
__device__ __forceinline__ uint packbf(float lo, float hi) {
  return (uint)f2bf_n(lo) | ((uint)f2bf_n(hi) << 16);
}

__device__ __forceinline__ int edge_at(const int* e32, int f, int i) {
  if (f) return (int)((const long long*)e32)[i];
  return e32[i];
}

// ---------------- K0: detect + prepW(W1^T hi/lo) + prepW2(W2^T hi/lo) -------
__global__ __launch_bounds__(256) void k_prep(const int* __restrict__ edges,
                                              const float* __restrict__ W1,
                                              const float* __restrict__ W2,
                                              int* __restrict__ flag,
                                              ushort* __restrict__ Wth,
                                              ushort* __restrict__ Wtl,
                                              ushort* __restrict__ W2th,
                                              ushort* __restrict__ W2tl) {
  const int bid = blockIdx.x, tid = threadIdx.x;
  if (bid == 0) {
    __shared__ int nz;
    if (tid == 0) nz = 0;
    __syncthreads();
    if (tid < 64) {
      int v = edges[2 * tid + 1];
      if (v != 0) atomicAdd(&nz, 1);
    }
    __syncthreads();
    if (tid == 0) *flag = (nz == 0) ? 1 : 0;  // 1 => int64
    return;
  }
  if (bid <= 256) {  // W1^T: [n][k], 128*512
    int i = (bid - 1) * 256 + tid;
    int n = i >> 9, k = i & 511;
    float w = W1[(size_t)k * HID + n];
    float back;
    Wth[i] = f2bf(w, back);
    Wtl[i] = f2bf_n(w - back);
    return;
  }
  {  // W2^T: [n][k], 64*128
    int j = (bid - 257) * 256 + tid;
    int n = j >> 7, k = j & 127;
    float w = W2[(size_t)k * OUTD + n];
    float back;
    W2th[j] = f2bf(w, back);
    W2tl[j] = f2bf_n(w - back);
  }
}

// ---------------- K1 body A: CSR bin pass (blocks 0..195) -------------------
__device__ void bin_body(int bid, ushort* smem16, const int* edges,
                         const int* flag, int* gCursor, int* staging) {
  int* cnt   = (int*)smem16;        // [NP]
  int* scn   = cnt + 128;           // [NP]
  int* base  = cnt + 256;           // [NP]
  int* cur   = cnt + 384;           // [NP]
  int* items = cnt + 512;           // [BINCH]
  const int tid = threadIdx.x;
  const int e0 = bid * BINCH;
  const int ecnt = min(BINCH, NE - e0);
  const int f = *flag;
  for (int i = tid; i < NP; i += 256) cnt[i] = 0;
  __syncthreads();
  for (int i = tid; i < ecnt; i += 256) {
    int d = edge_at(edges, f, NE + e0 + i);
    atomicAdd(&cnt[d >> 10], 1);
  }
  __syncthreads();
  if (tid == 0) {
    int s = 0;
    for (int p = 0; p < NP; ++p) { scn[p] = s; s += cnt[p]; }
  }
  __syncthreads();
  if (tid < NP) {
    base[tid] = (cnt[tid] > 0) ? atomicAdd(&gCursor[tid], cnt[tid]) : 0;
    cur[tid] = 0;
  }
  __syncthreads();
  for (int i = tid; i < ecnt; i += 256) {
    int d = edge_at(edges, f, NE + e0 + i);
    int s = edge_at(edges, f, e0 + i);
    int p = d >> 10;
    int lp = atomicAdd(&cur[p], 1);
    items[scn[p] + lp] = (s << 10) | (d & (PSZ - 1));
  }
  __syncthreads();
  for (int p = 0; p < NP; ++p) {
    int c = cnt[p];
    if (c == 0) continue;
    int gb = base[p];
    int* dst = staging + (size_t)p * PCAP;
    for (int i = tid; i < c; i += 256) {
      int gpos = gb + i;
      if (gpos < PCAP) dst[gpos] = items[scn[p] + i];
    }
  }
}

// ---------------- K1 body B: GEMM1, depth-2 A pipeline ----------------------
__device__ __forceinline__ void g1_loadA(const float* x, int row0, int tid,
                                         int kt, float4 ra[4]) {
#pragma unroll
  for (int i = 0; i < 4; ++i) {
    int flat = i * 256 + tid, r = flat >> 3, kq = flat & 7;
    int grow = row0 + r; if (grow > NN - 1) grow = NN - 1;
    ra[i] = *(const float4*)(x + (size_t)grow * IND + kt + kq * 4);
  }
}
__device__ __forceinline__ void g1_loadB(const ushort* Wth, const ushort* Wtl,
                                         int tid, int kt, uint4 rbh[2], uint4 rbl[2]) {
#pragma unroll
  for (int i = 0; i < 2; ++i) {
    int flat = i * 256 + tid, col = flat >> 2, kc = flat & 3;
    rbh[i] = *(const uint4*)(Wth + (size_t)col * IND + kt + kc * 8);
    rbl[i] = *(const uint4*)(Wtl + (size_t)col * IND + kt + kc * 8);
  }
}
__device__ __forceinline__ void g1_storeA(ushort* dAh, int tid, const float4 ra[4]) {
#pragma unroll
  for (int i = 0; i < 4; ++i) {
    int flat = i * 256 + tid, r = flat >> 3, kq = flat & 7;
    ushort4 hi;
    hi.x = f2bf_n(ra[i].x); hi.y = f2bf_n(ra[i].y);
    hi.z = f2bf_n(ra[i].z); hi.w = f2bf_n(ra[i].w);
    *(ushort4*)&dAh[r * 40 + kq * 4] = hi;
  }
}
__device__ __forceinline__ void g1_storeB(ushort* dBh, ushort* dBl, int tid,
                                          const uint4 rbh[2], const uint4 rbl[2]) {
#pragma unroll
  for (int i = 0; i < 2; ++i) {
    int flat = i * 256 + tid, col = flat >> 2, kc = flat & 3;
    *(uint4*)&dBh[col * 40 + kc * 8] = rbh[i];
    *(uint4*)&dBl[col * 40 + kc * 8] = rbl[i];
  }
}
__device__ __forceinline__ void g1_mfma(const ushort* buf, int wr, int wc,
                                        int lrow, int lkg, f32x4 acc[4][4]) {
  const ushort* bAh = buf;
  const ushort* bBh = buf + 5120;
  const ushort* bBl = buf + 10240;
  short8v ah[4], bh[4], bl[4];
#pragma unroll
  for (int m = 0; m < 4; ++m) {
    int r = wr * 64 + m * 16 + lrow;
    ah[m] = *(const short8v*)&bAh[r * 40 + lkg * 8];
  }
#pragma unroll
  for (int n = 0; n < 4; ++n) {
    int c = wc * 64 + n * 16 + lrow;
    bh[n] = *(const short8v*)&bBh[c * 40 + lkg * 8];
    bl[n] = *(const short8v*)&bBl[c * 40 + lkg * 8];
  }
#pragma unroll
  for (int m = 0; m < 4; ++m)
#pragma unroll
    for (int n = 0; n < 4; ++n) {
      acc[m][n] = __builtin_amdgcn_mfma_f32_16x16x32_bf16(ah[m], bh[n], acc[m][n], 0, 0, 0);
      acc[m][n] = __builtin_amdgcn_mfma_f32_16x16x32_bf16(ah[m], bl[n], acc[m][n], 0, 0, 0);
    }
}
__device__ __forceinline__ void g1_barrier() {
  asm volatile("s_waitcnt lgkmcnt(0)");
  __builtin_amdgcn_sched_barrier(0);
  __builtin_amdgcn_s_barrier();
  __builtin_amdgcn_sched_barrier(0);
}

__device__ void gemm1_body(int bid, ushort* smem, const float* x,
                           const ushort* Wth, const ushort* Wtl,
                           ushort* h1b) {
  ushort* sOut = smem;
  const int tid = threadIdx.x;
  const int lane = tid & 63, wid = tid >> 6;
  const int wr = wid >> 1, wc = wid & 1;
  const int lrow = lane & 15, lkg = lane >> 4;
  const int row0 = bid * 128;
  ushort* B0 = smem;            // buffer 0: Ah | Bh | Bl (15360 u16)
  ushort* B1 = smem + 15360;    // buffer 1

  f32x4 acc[4][4];
#pragma unroll
  for (int m = 0; m < 4; ++m)
#pragma unroll
    for (int n = 0; n < 4; ++n) acc[m][n] = (f32x4){0.f, 0.f, 0.f, 0.f};

  float4 raA0[4], raA1[4];
  uint4 rbh[2], rbl[2];

  g1_loadA(x, row0, tid, 0, raA0);
  g1_loadA(x, row0, tid, 32, raA1);
  g1_loadB(Wth, Wtl, tid, 0, rbh, rbl);
  g1_storeA(B0, tid, raA0);
  g1_storeB(B0 + 5120, B0 + 10240, tid, rbh, rbl);
  g1_barrier();

  for (int ss = 0; ss < 8; ++ss) {
    int s0 = 2 * ss;
    if (s0 + 2 < 16) g1_loadA(x, row0, tid, (s0 + 2) * 32, raA0);
    g1_loadB(Wth, Wtl, tid, (s0 + 1) * 32, rbh, rbl);
    g1_mfma(B0, wr, wc, lrow, lkg, acc);
    g1_storeA(B1, tid, raA1);
    g1_storeB(B1 + 5120, B1 + 10240, tid, rbh, rbl);
    g1_barrier();

    int s1 = s0 + 1;
    if (s1 + 2 < 16) {
      g1_loadA(x, row0, tid, (s1 + 2) * 32, raA1);
    }
    if (s1 + 1 < 16) {
      g1_loadB(Wth, Wtl, tid, (s1 + 1) * 32, rbh, rbl);
    }
    g1_mfma(B1, wr, wc, lrow, lkg, acc);
    if (s1 + 1 < 16) {
      g1_storeA(B0, tid, raA0);
      g1_storeB(B0 + 5120, B0 + 10240, tid, rbh, rbl);
      g1_barrier();
    }
  }

  __syncthreads();
#pragma unroll
  for (int m = 0; m < 4; ++m)
#pragma unroll
    for (int i = 0; i < 4; ++i) {
      int lr = wr * 64 + m * 16 + lkg * 4 + i;
#pragma unroll
      for (int n = 0; n < 4; ++n)
        sOut[lr * 136 + wc * 64 + n * 16 + lrow] = f2bf_n(acc[m][n][i]);
    }
  __syncthreads();
#pragma unroll
  for (int j = 0; j < 8; ++j) {
    int flat = j * 256 + tid;
    int r = flat >> 4, c = flat & 15;
    int grow = row0 + r;
    if (grow < NN)
      *(uint4*)(h1b + (size_t)grow * HID + c * 8) =
          *(const uint4*)&sOut[r * 136 + c * 8];
  }
}

// ---------------- K1: fused bin (first) + gemm1 -----------------------------
__global__ __launch_bounds__(256) void k_fused1(const float* __restrict__ x,
                                                const ushort* __restrict__ Wth,
                                                const ushort* __restrict__ Wtl,
                                                const int* __restrict__ edges,
                                                const int* __restrict__ flag,
                                                int* __restrict__ gCursor,
                                                int* __restrict__ staging,
                                                ushort* __restrict__ h1b) {
  __shared__ __align__(16) ushort smem[30720];
  if (blockIdx.x < NBIN)
    bin_body(blockIdx.x, smem, edges, flag, gCursor, staging);
  else
    gemm1_body(blockIdx.x - NBIN, smem, x, Wth, Wtl, h1b);
}

// ---------------- CSR pass 2: counting sort (parallel self-scan) ------------
__global__ __launch_bounds__(256) void k_csrpart(const int* __restrict__ staging,
                                                 const int* __restrict__ gCursor,
                                                 int* __restrict__ offsets,
                                                 int* __restrict__ csr_src) {
  __shared__ int cnt[PSZ];
  __shared__ int cur[PSZ];
  __shared__ int tsum[256];
  __shared__ int gc[256];
  __shared__ int srcbuf[PCAP];   // 80 KB
  const int tid = threadIdx.x;
  const int p = blockIdx.x;
  // parallel inclusive scan of gCursor (replaces serial tid-0 loop: 98
  // dependent L2 reads ~= 5-10us of serial prologue per block)
  gc[tid] = (tid < NP) ? min(gCursor[tid], PCAP) : 0;
  for (int i = tid; i < PSZ; i += 256) { cnt[i] = 0; cur[i] = 0; }
  if (p == NP - 1 && tid == 0) offsets[NN] = NE;
  __syncthreads();
  for (int off = 1; off < 128; off <<= 1) {
    int t = (tid >= off) ? gc[tid - off] : 0;
    __syncthreads();
    gc[tid] += t;
    __syncthreads();
  }
  const int tot = min(gCursor[p], PCAP);
  const int gbase = gc[p] - tot;
  const int* st = staging + (size_t)p * PCAP;
  for (int i = tid; i < tot; i += 256) atomicAdd(&cnt[st[i] & (PSZ - 1)], 1);
  __syncthreads();
  int b0 = tid * 4;
  int c0 = cnt[b0], c1 = cnt[b0 + 1], c2 = cnt[b0 + 2], c3 = cnt[b0 + 3];
  int ls = c0 + c1 + c2 + c3;
  tsum[tid] = ls;
  __syncthreads();
  for (int off = 1; off < 256; off <<= 1) {
    int t = (tid >= off) ? tsum[tid - off] : 0;
    __syncthreads();
    tsum[tid] += t;
    __syncthreads();
  }
  int ebase = tsum[tid] - ls;
  cnt[b0] = ebase;
  cnt[b0 + 1] = ebase + c0;
  cnt[b0 + 2] = ebase + c0 + c1;
  cnt[b0 + 3] = ebase + c0 + c1 + c2;
  __syncthreads();
  for (int i = tid; i < PSZ; i += 256) {
    int node = p * PSZ + i;
    if (node < NN) offsets[node] = gbase + cnt[i];
  }
  for (int i = tid; i < tot; i += 256) {
    int item = st[i];
    int dl = item & (PSZ - 1);
    int lp = atomicAdd(&cur[dl], 1);
    srcbuf[cnt[dl] + lp] = item >> 10;
  }
  __syncthreads();
  for (int i = tid; i < tot; i += 256) csr_src[gbase + i] = srcbuf[i];
}

// ---------------- Aggregation 1 (+b1): full-row uint4 gathers ---------------
// Quarter-wave groups: 16 lanes x 16B = one full 256B h1 row per instruction
// (was 2 instrs/row). 2 chains -> 8 edges in flight, half the issue count.
__global__ __launch_bounds__(256) void k_agg1(const ushort* __restrict__ h1b,
                                              const int* __restrict__ offsets,
                                              const int* __restrict__ csr_src,
                                              const float* __restrict__ b1,
                                              ushort* __restrict__ aggb) {
  int w = threadIdx.x >> 6, lane = threadIdx.x & 63;
  int n = blockIdx.x * 4 + w;
  if (n >= NN) return;
  int beg = offsets[n], end = offsets[n + 1];
  int q4 = lane >> 4, ch = lane & 15;
  const uint4* h = (const uint4*)h1b;  // 16 uint4 per row (128 bf16)
  float4 aL = {0.f, 0.f, 0.f, 0.f}, aH = {0.f, 0.f, 0.f, 0.f};
  float4 cL = {0.f, 0.f, 0.f, 0.f}, cH = {0.f, 0.f, 0.f, 0.f};
  int i = beg + q4;
  for (; i + 4 < end; i += 8) {
    uint4 v0 = h[(size_t)csr_src[i] * 16 + ch];
    uint4 v1 = h[(size_t)csr_src[i + 4] * 16 + ch];
    aL.x += bflo(v0.x); aL.y += bfhi(v0.x); aL.z += bflo(v0.y); aL.w += bfhi(v0.y);
    aH.x += bflo(v0.z); aH.y += bfhi(v0.z); aH.z += bflo(v0.w); aH.w += bfhi(v0.w);
    cL.x += bflo(v1.x); cL.y += bfhi(v1.x); cL.z += bflo(v1.y); cL.w += bfhi(v1.y);
    cH.x += bflo(v1.z); cH.y += bfhi(v1.z); cH.z += bflo(v1.w); cH.w += bfhi(v1.w);
  }
  for (; i < end; i += 4) {
    uint4 v = h[(size_t)csr_src[i] * 16 + ch];
    aL.x += bflo(v.x); aL.y += bfhi(v.x); aL.z += bflo(v.y); aL.w += bfhi(v.y);
    aH.x += bflo(v.z); aH.y += bfhi(v.z); aH.z += bflo(v.w); aH.w += bfhi(v.w);
  }
  aL.x += cL.x; aL.y += cL.y; aL.z += cL.z; aL.w += cL.w;
  aH.x += cH.x; aH.y += cH.y; aH.z += cH.z; aH.w += cH.w;
  // cross-group reduce (4 groups at stride 16)
  aL.x += __shfl_xor(aL.x, 16); aL.x += __shfl_xor(aL.x, 32);
  aL.y += __shfl_xor(aL.y, 16); aL.y += __shfl_xor(aL.y, 32);
  aL.z += __shfl_xor(aL.z, 16); aL.z += __shfl_xor(aL.z, 32);
  aL.w += __shfl_xor(aL.w, 16); aL.w += __shfl_xor(aL.w, 32);
  aH.x += __shfl_xor(aH.x, 16); aH.x += __shfl_xor(aH.x, 32);
  aH.y += __shfl_xor(aH.y, 16); aH.y += __shfl_xor(aH.y, 32);
  aH.z += __shfl_xor(aH.z, 16); aH.z += __shfl_xor(aH.z, 32);
  aH.w += __shfl_xor(aH.w, 16); aH.w += __shfl_xor(aH.w, 32);
  if (q4 == 0) {
    float4 bLo = *(const float4*)(b1 + 8 * ch);
    float4 bHi = *(const float4*)(b1 + 8 * ch + 4);
    uint4 o;
    o.x = packbf(aL.x + bLo.x, aL.y + bLo.y);
    o.y = packbf(aL.z + bLo.z, aL.w + bLo.w);
    o.z = packbf(aH.x + bHi.x, aH.y + bHi.y);
    o.w = packbf(aH.z + bHi.z, aH.w + bHi.w);
    ((uint4*)aggb)[(size_t)n * 16 + ch] = o;
  }
}

// ---------------- BN stats (bf16 input) ------------------------------------
__global__ __launch_bounds__(256) void k_bnstats(const ushort* __restrict__ aggb,
                                                 float* __restrict__ gsum,
                                                 float* __restrict__ gsq) {
  __shared__ float2 ss[4][64], qq[4][64];
  int tid = threadIdx.x;
  int lane = tid & 63, g = tid >> 6;
  int r0 = blockIdx.x * 128;
  const uint* a = (const uint*)aggb;
  float2 s = {0.f, 0.f}, q = {0.f, 0.f};
  for (int k = 0; k < 32; ++k) {
    int r = r0 + g + 4 * k;
    if (r < NN) {
      uint v = a[(size_t)r * 64 + lane];
      float lo = bflo(v), hi = bfhi(v);
      s.x += lo; s.y += hi;
      q.x += lo * lo; q.y += hi * hi;
    }
  }
  ss[g][lane] = s; qq[g][lane] = q;
  __syncthreads();
  if (g == 0) {
    float2 S = ss[0][lane], Q = qq[0][lane];
#pragma unroll
    for (int gg = 1; gg < 4; ++gg) {
      S.x += ss[gg][lane].x; S.y += ss[gg][lane].y;
      Q.x += qq[gg][lane].x; Q.y += qq[gg][lane].y;
    }
    atomicAdd(&gsum[2 * lane], S.x);
    atomicAdd(&gsum[2 * lane + 1], S.y);
    atomicAdd(&gsq[2 * lane], Q.x);
    atomicAdd(&gsq[2 * lane + 1], Q.y);
  }
}

// ---------------- GEMM2 via MFMA (BN-finalize fused in-block) ---------------
__global__ __launch_bounds__(256) void k_gemm2m(const ushort* __restrict__ aggb,
                                                const ushort* __restrict__ W2th,
                                                const ushort* __restrict__ W2tl,
                                                const float* __restrict__ gsum,
                                                const float* __restrict__ gsq,
                                                const float* __restrict__ gamma,
                                                const float* __restrict__ beta,
                                                ushort* __restrict__ h2b) {
  __shared__ __align__(16) ushort smem[27648]; // Bh 8704 | Bl 8704 | Adbuf 10240
  __shared__ float isgS[128], bbS[128];
  ushort* sBh = smem;            // [64][136]
  ushort* sBl = smem + 8704;     // [64][136]
  ushort* sA  = smem + 17408;    // 2 x [128][40]
  ushort* sOut = sA;             // epilogue alias: [128][72]
  const int tid = threadIdx.x;
  const int lane = tid & 63, wid = tid >> 6;
  const int wr = wid >> 1, wc = wid & 1;
  const int lrow = lane & 15, lkg = lane >> 4;
  const int row0 = blockIdx.x * 128;

  if (tid < 128) {  // fused bnfin (redundant per block, trivial)
    float mean = gsum[tid] * (1.f / NN);
    float var = fmaxf(gsq[tid] * (1.f / NN) - mean * mean, 0.f);
    float inv = 1.f / sqrtf(var + BN_EPS);
    float g = gamma[tid] * inv;
    isgS[tid] = g;
    bbS[tid] = beta[tid] - mean * g;
  }
#pragma unroll
  for (int i = 0; i < 4; ++i) {
    int c = i * 256 + tid;
    int n = c >> 4, kq = c & 15;
    *(uint4*)&sBh[n * 136 + kq * 8] = *(const uint4*)(W2th + (size_t)n * HID + kq * 8);
    *(uint4*)&sBl[n * 136 + kq * 8] = *(const uint4*)(W2tl + (size_t)n * HID + kq * 8);
  }

  f32x4 acc[4][2];
#pragma unroll
  for (int m = 0; m < 4; ++m)
#pragma unroll
    for (int n = 0; n < 2; ++n) acc[m][n] = (f32x4){0.f, 0.f, 0.f, 0.f};

  uint4 rA[2];
#pragma unroll
  for (int i = 0; i < 2; ++i) {
    int c = i * 256 + tid;
    int r = c >> 2, cq = c & 3;
    int grow = row0 + r; if (grow > NN - 1) grow = NN - 1;
    rA[i] = *(const uint4*)(aggb + (size_t)grow * HID + cq * 8);
  }
  __syncthreads();  // isgS/bbS + B visible

  {
    ushort* dA = sA;
#pragma unroll
    for (int i = 0; i < 2; ++i) {
      int c = i * 256 + tid;
      int r = c >> 2, cq = c & 3;
      int k0 = cq * 8;
      uint4 v = rA[i];
      uint o[4];
      const uint* vv = (const uint*)&v;
#pragma unroll
      for (int j = 0; j < 4; ++j) {
        float lo = bflo(vv[j]), hi = bfhi(vv[j]);
        lo = fmaxf(fmaf(lo, isgS[k0 + 2 * j], bbS[k0 + 2 * j]), 0.f);
        hi = fmaxf(fmaf(hi, isgS[k0 + 2 * j + 1], bbS[k0 + 2 * j + 1]), 0.f);
        o[j] = packbf(lo, hi);
      }
      *(uint4*)&dA[r * 40 + cq * 8] = *(const uint4*)o;
    }
  }

  int cur = 0;
  for (int s = 0; s < 4; ++s) {
    __syncthreads();
    const int kt = s * 32;
    if (s < 3) {
      int ktn = kt + 32;
#pragma unroll
      for (int i = 0; i < 2; ++i) {
        int c = i * 256 + tid;
        int r = c >> 2, cq = c & 3;
        int grow = row0 + r; if (grow > NN - 1) grow = NN - 1;
        rA[i] = *(const uint4*)(aggb + (size_t)grow * HID + ktn + cq * 8);
      }
    }
    {
      const ushort* bA = sA + cur * 5120;
      short8v ah[4], bh[2], bl[2];
#pragma unroll
      for (int m = 0; m < 4; ++m) {
        int r = wr * 64 + m * 16 + lrow;
        ah[m] = *(const short8v*)&bA[r * 40 + lkg * 8];
      }
#pragma unroll
      for (int n = 0; n < 2; ++n) {
        int c = wc * 32 + n * 16 + lrow;
        bh[n] = *(const short8v*)&sBh[c * 136 + kt + lkg * 8];
        bl[n] = *(const short8v*)&sBl[c * 136 + kt + lkg * 8];
      }
#pragma unroll
      for (int m = 0; m < 4; ++m)
#pragma unroll
        for (int n = 0; n < 2; ++n) {
          acc[m][n] = __builtin_amdgcn_mfma_f32_16x16x32_bf16(ah[m], bh[n], acc[m][n], 0, 0, 0);
          acc[m][n] = __builtin_amdgcn_mfma_f32_16x16x32_bf16(ah[m], bl[n], acc[m][n], 0, 0, 0);
        }
    }
    if (s < 3) {
      ushort* dA = sA + (cur ^ 1) * 5120;
      int k0b = (s + 1) * 32;
#pragma unroll
      for (int i = 0; i < 2; ++i) {
        int c = i * 256 + tid;
        int r = c >> 2, cq = c & 3;
        int k0 = k0b + cq * 8;
        uint4 v = rA[i];
        uint o[4];
        const uint* vv = (const uint*)&v;
#pragma unroll
        for (int j = 0; j < 4; ++j) {
          float lo = bflo(vv[j]), hi = bfhi(vv[j]);
          lo = fmaxf(fmaf(lo, isgS[k0 + 2 * j], bbS[k0 + 2 * j]), 0.f);
          hi = fmaxf(fmaf(hi, isgS[k0 + 2 * j + 1], bbS[k0 + 2 * j + 1]), 0.f);
          o[j] = packbf(lo, hi);
        }
        *(uint4*)&dA[r * 40 + cq * 8] = *(const uint4*)o;
      }
    }
    cur ^= 1;
  }

  __syncthreads();
#pragma unroll
  for (int m = 0; m < 4; ++m)
#pragma unroll
    for (int i = 0; i < 4; ++i) {
      int lr = wr * 64 + m * 16 + lkg * 4 + i;
#pragma unroll
      for (int n = 0; n < 2; ++n)
        sOut[lr * 72 + wc * 32 + n * 16 + lrow] = f2bf_n(acc[m][n][i]);
    }
  __syncthreads();
#pragma unroll
  for (int i = 0; i < 4; ++i) {
    int c = i * 256 + tid;
    int r = c >> 3, cq = c & 7;
    int grow = row0 + r;
    if (grow < NN)
      *(uint4*)(h2b + (size_t)grow * OUTD + cq * 8) =
          *(const uint4*)&sOut[r * 72 + cq * 8];
  }
}

// ---------------- Agg2 + b2 + L2 normalize: full-row uint2 gathers ----------
// Quarter-wave groups: 16 lanes x 8B = one full 128B h2 row per instruction.
__global__ __launch_bounds__(256) void k_agg2norm(const ushort* __restrict__ h2b,
                                                  const int* __restrict__ offsets,
                                                  const int* __restrict__ csr_src,
                                                  const float* __restrict__ b2,
                                                  float* __restrict__ out) {
  int w = threadIdx.x >> 6, lane = threadIdx.x & 63;
  int n = blockIdx.x * 4 + w;
  if (n >= NN) return;
  int beg = offsets[n], end = offsets[n + 1];
  int q4 = lane >> 4, ch = lane & 15;
  const uint2* h = (const uint2*)h2b;  // 16 uint2 per row (64 bf16)
  float4 a = {0.f, 0.f, 0.f, 0.f}, c4 = {0.f, 0.f, 0.f, 0.f};
  int i = beg + q4;
  for (; i + 4 < end; i += 8) {
    uint2 v0 = h[(size_t)csr_src[i] * 16 + ch];
    uint2 v1 = h[(size_t)csr_src[i + 4] * 16 + ch];
    a.x += bflo(v0.x); a.y += bfhi(v0.x); a.z += bflo(v0.y); a.w += bfhi(v0.y);
    c4.x += bflo(v1.x); c4.y += bfhi(v1.x); c4.z += bflo(v1.y); c4.w += bfhi(v1.y);
  }
  for (; i < end; i += 4) {
    uint2 v = h[(size_t)csr_src[i] * 16 + ch];
    a.x += bflo(v.x); a.y += bfhi(v.x); a.z += bflo(v.y); a.w += bfhi(v.y);
  }
  a.x += c4.x; a.y += c4.y; a.z += c4.z; a.w += c4.w;
  a.x += __shfl_xor(a.x, 16); a.x += __shfl_xor(a.x, 32);
  a.y += __shfl_xor(a.y, 16); a.y += __shfl_xor(a.y, 32);
  a.z += __shfl_xor(a.z, 16); a.z += __shfl_xor(a.z, 32);
  a.w += __shfl_xor(a.w, 16); a.w += __shfl_xor(a.w, 32);
  float4 b = *(const float4*)(b2 + 4 * ch);
  a.x += b.x; a.y += b.y; a.z += b.z; a.w += b.w;
  float q = a.x * a.x + a.y * a.y + a.z * a.z + a.w * a.w;
#pragma unroll
  for (int off = 8; off > 0; off >>= 1) q += __shfl_xor(q, off);
  float norm = sqrtf(q);
  float scale = 1.f / fmaxf(norm, 1e-12f);
  if (q4 == 0) {
    float4 o = {a.x * scale, a.y * scale, a.z * scale, a.w * scale};
    *(float4*)(out + (size_t)n * OUTD + 4 * ch) = o;
  }
}

// ---------------- launch ----------------------------------------------------
extern "C" void kernel_launch(void* const* d_in, const int* in_sizes, int n_in,
                              void* d_out, int out_size, void* d_ws, size_t ws_size,
                              hipStream_t stream) {
  const float* x     = (const float*)d_in[0];
  const int*   edges = (const int*)d_in[1];
  const float* W1    = (const float*)d_in[2];
  const float* b1    = (const float*)d_in[3];
  const float* W2    = (const float*)d_in[4];
  const float* b2    = (const float*)d_in[5];
  const float* gamma = (const float*)d_in[6];
  const float* beta  = (const float*)d_in[7];

  char* ws = (char*)d_ws;
  ushort* h1b     = (ushort*)(ws);                // 25.6 MB
  ushort* aggb    = (ushort*)(ws + 26000000);     // 25.6 MB (bf16)
  int*    csr_src = (int*)(ws + 77500000);        // 6.4 MB
  int*    offsets = (int*)(ws + 84000000);        // 100001 ints
  int*    staging = (int*)(ws + 84400128);        // 98*20480*4 = 8,028,160 B
  int*    gCursor = (int*)(ws + 92428544);        // 98 ints
  float*  gsum    = (float*)(ws + 92429568);      // 128 f
  float*  gsq     = (float*)(ws + 92430080);      // 128 f
  int*    eflag   = (int*)(ws + 92431616);        // 1 int
  ushort* Wth     = (ushort*)(ws + 92432128);     // 128 KB
  ushort* Wtl     = (ushort*)(ws + 92563200);     // 128 KB
  ushort* W2th    = (ushort*)(ws + 92694272);     // 16 KB
  ushort* W2tl    = (ushort*)(ws + 92710656);     // 16 KB
  ushort* h2b     = h1b;                          // reuse (h1b dead after agg1)

  if (ws_size < 92727040) return;  // scratch layout requirement

  // zero gCursor + gsum + gsq (2 KB)
  hipMemsetAsync(gCursor, 0, 2048, stream);

  k_prep<<<289, 256, 0, stream>>>(edges, W1, W2, eflag, Wth, Wtl, W2th, W2tl);
  k_fused1<<<NBIN + 782, 256, 0, stream>>>(x, Wth, Wtl, edges, eflag,
                                           gCursor, staging, h1b);
  k_csrpart<<<NP, 256, 0, stream>>>(staging, gCursor, offsets, csr_src);
  k_agg1<<<25000, 256, 0, stream>>>(h1b, offsets, csr_src, b1, aggb);
  k_bnstats<<<782, 256, 0, stream>>>(aggb, gsum, gsq);
  k_gemm2m<<<782, 256, 0, stream>>>(aggb, W2th, W2tl, gsum, gsq, gamma, beta, h2b);
  k_agg2norm<<<25000, 256, 0, stream>>>(h2b, offsets, csr_src, b2,
                                        (float*)d_out);
}